// Round 1
// baseline (631.014 us; speedup 1.0000x reference)
//
#include <hip/hip_runtime.h>

#define B_   16
#define L_   1536
#define D_   512
#define DFF_ 2048
#define NM   64
#define HID  256

typedef short short8  __attribute__((ext_vector_type(8)));
typedef short short4v __attribute__((ext_vector_type(4)));
typedef float f32x4   __attribute__((ext_vector_type(4)));

__device__ __forceinline__ float b2f(short s) {
  unsigned int u = ((unsigned int)(unsigned short)s) << 16;
  float f; __builtin_memcpy(&f, &u, 4); return f;
}
__device__ __forceinline__ short f2b(float f) {
  unsigned int u; __builtin_memcpy(&u, &f, 4);
  u += 0x7fffu + ((u >> 16) & 1u);
  return (short)(u >> 16);
}
__device__ __forceinline__ f32x4 zero4() {
  f32x4 v; v[0]=0.f; v[1]=0.f; v[2]=0.f; v[3]=0.f; return v;
}

#define MFMA(a,b,c) __builtin_amdgcn_mfma_f32_16x16x32_bf16((a),(b),(c),0,0,0)
// XOR-swizzled LDS offset (shorts) for 64-short rows: row*64 + (grp^(row&7))*8
#define SWZ(row, grp) (((row) << 6) + ((((grp) ^ ((row) & 7))) << 3))
// async 16B/lane global->LDS (m97: width 16 => global_load_lds_dwordx4)
#define GLDS16(gp, lp) __builtin_amdgcn_global_load_lds( \
    (const __attribute__((address_space(1))) void*)(gp), \
    (__attribute__((address_space(3))) void*)(lp), 16, 0, 0)

// ---------------- guard: zero output (ws too small diagnostic) ----------------
__global__ __launch_bounds__(256) void zero_out(float* __restrict__ o, int n) {
  int i = blockIdx.x * 256 + threadIdx.x;
  if (i < n) o[i] = 0.f;
}

// ---------------- fused prep: 4x f32->bf16 convert + DFT tables ----------------
// blocks [0,1024): conv1 | [1024,2048): conv2 | [2048,2176): d1w1 |
// [2176,2304): d2w1 | [2304,3072): tcs | [3072,3840): basis
__global__ __launch_bounds__(256) void prep_all(
    const float* __restrict__ conv1_w, const float* __restrict__ conv2_w,
    const float* __restrict__ d1_w1,  const float* __restrict__ d2_w1,
    short* __restrict__ c1, short* __restrict__ c2,
    short* __restrict__ dw1, short* __restrict__ dw2,
    short* __restrict__ tcs, short* __restrict__ basis)
{
  int blk = blockIdx.x;
  if (blk < 2304) {   // converts: pick source/dest
    const float* s; short* d; int i;
    if (blk < 1024)      { s = conv1_w; d = c1;  i = blk * 256 + threadIdx.x; }
    else if (blk < 2048) { s = conv2_w; d = c2;  i = (blk - 1024) * 256 + threadIdx.x; }
    else if (blk < 2176) { s = d1_w1;   d = dw1; i = (blk - 2048) * 256 + threadIdx.x; }
    else                 { s = d2_w1;   d = dw2; i = (blk - 2176) * 256 + threadIdx.x; }
    f32x4 v = ((const f32x4*)s)[i];
    short4v o;
    #pragma unroll
    for (int j = 0; j < 4; ++j) o[j] = f2b(v[j]);
    ((short4v*)d)[i] = o;
    return;
  }
  if (blk < 3072) {   // tcs[m][l], m<64: cos; m>=64: -sin
    int i = (blk - 2304) * 256 + threadIdx.x;
    int m = i / L_, l = i - m * L_;
    int mm = (m < 64) ? m : (m - 64);
    int r = (mm * l) % L_;
    float th = (float)r * (6.283185307179586f / (float)L_);
    float s, c; __sincosf(th, &s, &c);
    tcs[i] = f2b((m < 64) ? c : -s);
    return;
  }
  {   // basis[l][k]
    int i = (blk - 3072) * 256 + threadIdx.x;
    int l = i >> 7, k = i & 127;
    int m = (k < 64) ? k : (k - 64);
    int r = (m * l) % L_;
    float th = (float)r * (6.283185307179586f / (float)L_);
    float s, c; __sincosf(th, &s, &c);
    float v = (k < 64) ? ((m == 0) ? 1.f : 2.f) * (1.f / (float)L_) * c
                       : (-2.f / (float)L_) * s;
    basis[i] = f2b(v);
  }
}

// ---------------- w[d][e][m] f32 -> wt[m][e][d] bf16; z<4 real, z>=4 imag ----------------
__global__ __launch_bounds__(256) void transpose_w(
    const float* __restrict__ wre, const float* __restrict__ wim,
    short* __restrict__ wtr, short* __restrict__ wti)
{
  __shared__ float tile[64][17];
  int dc = blockIdx.x, e = blockIdx.y, t = threadIdx.x;
  int zz = blockIdx.z;
  const float* w = (zz < 4) ? wre : wim;
  short* wt      = (zz < 4) ? wtr : wti;
  int mBase = (zz & 3) * 16;
  {
    int dl = t >> 2, mg = t & 3;
    f32x4 v = *(const f32x4*)(w + ((long)(dc * 64 + dl) * 512 + e) * 64 + mBase + mg * 4);
    tile[dl][mg*4+0] = v[0]; tile[dl][mg*4+1] = v[1];
    tile[dl][mg*4+2] = v[2]; tile[dl][mg*4+3] = v[3];
  }
  __syncthreads();
  if (t < 128) {
    int mr = t >> 3, dg = t & 7;
    short8 o;
    #pragma unroll
    for (int j = 0; j < 8; ++j) o[j] = f2b(tile[dg * 8 + j][mr]);
    *(short8*)(wt + ((long)(mBase + mr) * 512 + e) * 512 + dc * 64 + dg * 8) = o;
  }
}

// ---------------- x[b][l][d] f32 -> xt[b][d][l] bf16 ----------------
__global__ __launch_bounds__(256) void transpose_x(const float* __restrict__ x,
                                                   short* __restrict__ xt) {
  __shared__ float tile[64][65];
  int dc = blockIdx.x, lc = blockIdx.y, b = blockIdx.z, t = threadIdx.x;
  const float* xb = x + (long)b * L_ * D_;
  #pragma unroll
  for (int i = 0; i < 4; ++i) {
    int idx = i * 256 + t; int ll = idx >> 4, dg = idx & 15;
    f32x4 v = *(const f32x4*)(xb + (long)(lc * 64 + ll) * D_ + dc * 64 + dg * 4);
    tile[ll][dg*4+0] = v[0]; tile[ll][dg*4+1] = v[1];
    tile[ll][dg*4+2] = v[2]; tile[ll][dg*4+3] = v[3];
  }
  __syncthreads();
  #pragma unroll
  for (int i = 0; i < 2; ++i) {
    int idx = i * 256 + t; int dl = idx >> 3, lg = idx & 7;
    short8 o;
    #pragma unroll
    for (int j = 0; j < 8; ++j) o[j] = f2b(tile[lg * 8 + j][dl]);
    *(short8*)(xt + ((long)b * D_ + dc * 64 + dl) * L_ + lc * 64 + lg * 8) = o;
  }
}

// ---------------- 64x64-tile bf16 MFMA GEMM (dbuf + counted vmcnt) ----------------
// C = act(A*W^T + bias); out addr = row*csr + col*csc (bf16).
// 2-phase pipeline: stage tile t+1 while computing tile t; vmcnt(4) in steady
// state (4 GLDS16/thread/tile stay in flight across the raw barrier), vmcnt(0)
// only on the last tile. Raw s_barrier (no compiler vmcnt(0) drain).
template<bool RELU, bool HASBIAS>
__global__ __launch_bounds__(256) void gemm64(
    const short* __restrict__ A, long ldA,
    const short* __restrict__ W, long ldW,
    const float* __restrict__ bias,
    short* __restrict__ outB, long csr, long csc, int K)
{
  __shared__ short lA[2][64 * 64];
  __shared__ short lW[2][64 * 64];
  const int t = threadIdx.x, lane = t & 63, wid = t >> 6;
  const int quad = lane >> 4, l15 = lane & 15;
  const int wm = (wid & 1) * 32, wn = (wid >> 1) * 32;
  const long row0 = (long)blockIdx.x * 64, col0 = (long)blockIdx.y * 64;
  const short* Ab = A + row0 * ldA;
  const short* Wb = W + col0 * ldW;

  int srcrow[2]; long srcoff[2];
  #pragma unroll
  for (int i = 0; i < 2; ++i) {
    int c = wid * 2 + i;
    int r = c * 8 + (lane >> 3);
    int g = (lane & 7) ^ (r & 7);
    srcrow[i] = r; srcoff[i] = g * 8;
  }

  f32x4 acc[2][2];
  #pragma unroll
  for (int i = 0; i < 2; ++i)
    #pragma unroll
    for (int j = 0; j < 2; ++j) acc[i][j] = zero4();

  const int nk = K >> 6;
  // prologue: stage tile 0 (and tile 1 if present)
  #pragma unroll
  for (int i = 0; i < 2; ++i) {
    int c = wid * 2 + i;
    GLDS16(Ab + (long)srcrow[i] * ldA + srcoff[i], lA[0] + c * 512);
    GLDS16(Wb + (long)srcrow[i] * ldW + srcoff[i], lW[0] + c * 512);
  }
  if (nk > 1) {
    #pragma unroll
    for (int i = 0; i < 2; ++i) {
      int c = wid * 2 + i;
      GLDS16(Ab + (long)srcrow[i] * ldA + 64 + srcoff[i], lA[1] + c * 512);
      GLDS16(Wb + (long)srcrow[i] * ldW + 64 + srcoff[i], lW[1] + c * 512);
    }
  }

  for (int it = 0; it < nk; ++it) {
    if (it + 1 < nk) asm volatile("s_waitcnt vmcnt(4)" ::: "memory");
    else             asm volatile("s_waitcnt vmcnt(0)" ::: "memory");
    __builtin_amdgcn_s_barrier();   // all waves' tile-it loads are in LDS
    const int cur = it & 1;
    const short* bufA = lA[cur];
    const short* bufW = lW[cur];
    #pragma unroll
    for (int ks = 0; ks < 2; ++ks) {
      int gq = ks * 4 + quad;
      short8 a0 = *(const short8*)&bufA[SWZ(wm + l15, gq)];
      short8 a1 = *(const short8*)&bufA[SWZ(wm + 16 + l15, gq)];
      short8 b0 = *(const short8*)&bufW[SWZ(wn + l15, gq)];
      short8 b1 = *(const short8*)&bufW[SWZ(wn + 16 + l15, gq)];
      acc[0][0] = MFMA(a0, b0, acc[0][0]);
      acc[0][1] = MFMA(a0, b1, acc[0][1]);
      acc[1][0] = MFMA(a1, b0, acc[1][0]);
      acc[1][1] = MFMA(a1, b1, acc[1][1]);
    }
    asm volatile("s_waitcnt lgkmcnt(0)" ::: "memory");
    __builtin_amdgcn_s_barrier();   // all waves done reading buf[cur]
    const long kn = (long)(it + 2) * 64;
    if (kn < K) {
      #pragma unroll
      for (int i = 0; i < 2; ++i) {
        int c = wid * 2 + i;
        GLDS16(Ab + (long)srcrow[i] * ldA + kn + srcoff[i], lA[cur] + c * 512);
        GLDS16(Wb + (long)srcrow[i] * ldW + kn + srcoff[i], lW[cur] + c * 512);
      }
    }
  }

  #pragma unroll
  for (int ni = 0; ni < 2; ++ni) {
    long col = col0 + wn + ni * 16 + l15;
    float bvv = HASBIAS ? bias[col] : 0.f;
    #pragma unroll
    for (int mi = 0; mi < 2; ++mi) {
      #pragma unroll
      for (int r = 0; r < 4; ++r) {
        long row = row0 + wm + mi * 16 + quad * 4 + r;
        float v = acc[mi][ni][r];
        if (HASBIAS) v += bvv;
        if (RELU)    v = fmaxf(v, 0.f);
        outB[row * csr + col * csc] = f2b(v);
      }
    }
  }
}

// ---------------- 128x128-tile bf16 MFMA GEMM (dbuf + counted vmcnt) ----------------
// Same 2-phase pipeline as gemm64; 8 GLDS16/thread/tile -> vmcnt(8) steady state.
template<bool RELU, bool HASBIAS, bool HASRES, bool RESB>
__global__ __launch_bounds__(256) void gemm128(
    const short* __restrict__ A, long ldA, long Az,
    const short* __restrict__ W, long ldW, long Wz,
    const float* __restrict__ bias,
    const void* __restrict__ res, long ldres, long resZ,
    short* __restrict__ outB, long ldC, long Cz, int K)
{
  __shared__ short lA[2][128 * 64];
  __shared__ short lW[2][128 * 64];
  const int t = threadIdx.x, lane = t & 63, wid = t >> 6;
  const int quad = lane >> 4, l15 = lane & 15;
  const int wm = (wid & 1) * 64, wn = (wid >> 1) * 64;
  const long row0 = (long)blockIdx.x * 128, col0 = (long)blockIdx.y * 128;
  const int z = blockIdx.z;
  const short* Ab = A + (long)z * Az + row0 * ldA;
  const short* Wb = W + (long)z * Wz + col0 * ldW;

  int srcrow[4]; long srcoff[4];
  #pragma unroll
  for (int i = 0; i < 4; ++i) {
    int c = wid * 4 + i;
    int r = c * 8 + (lane >> 3);
    int g = (lane & 7) ^ (r & 7);
    srcrow[i] = r; srcoff[i] = g * 8;
  }

  f32x4 acc[4][4];
  #pragma unroll
  for (int i = 0; i < 4; ++i)
    #pragma unroll
    for (int j = 0; j < 4; ++j) acc[i][j] = zero4();

  const int nk = K >> 6;
  // prologue: stage tile 0 (and tile 1 if present)
  #pragma unroll
  for (int i = 0; i < 4; ++i) {
    int c = wid * 4 + i;
    GLDS16(Ab + (long)srcrow[i] * ldA + srcoff[i], lA[0] + c * 512);
    GLDS16(Wb + (long)srcrow[i] * ldW + srcoff[i], lW[0] + c * 512);
  }
  if (nk > 1) {
    #pragma unroll
    for (int i = 0; i < 4; ++i) {
      int c = wid * 4 + i;
      GLDS16(Ab + (long)srcrow[i] * ldA + 64 + srcoff[i], lA[1] + c * 512);
      GLDS16(Wb + (long)srcrow[i] * ldW + 64 + srcoff[i], lW[1] + c * 512);
    }
  }

  for (int it = 0; it < nk; ++it) {
    if (it + 1 < nk) asm volatile("s_waitcnt vmcnt(8)" ::: "memory");
    else             asm volatile("s_waitcnt vmcnt(0)" ::: "memory");
    __builtin_amdgcn_s_barrier();   // all waves' tile-it loads are in LDS
    const int cur = it & 1;
    const short* bufA = lA[cur];
    const short* bufW = lW[cur];
    #pragma unroll
    for (int ks = 0; ks < 2; ++ks) {
      int gq = ks * 4 + quad;
      short8 av[4], bv[4];
      #pragma unroll
      for (int mi = 0; mi < 4; ++mi) av[mi] = *(const short8*)&bufA[SWZ(wm + mi * 16 + l15, gq)];
      #pragma unroll
      for (int ni = 0; ni < 4; ++ni) bv[ni] = *(const short8*)&bufW[SWZ(wn + ni * 16 + l15, gq)];
      #pragma unroll
      for (int mi = 0; mi < 4; ++mi)
        #pragma unroll
        for (int ni = 0; ni < 4; ++ni)
          acc[mi][ni] = MFMA(av[mi], bv[ni], acc[mi][ni]);
    }
    asm volatile("s_waitcnt lgkmcnt(0)" ::: "memory");
    __builtin_amdgcn_s_barrier();   // all waves done reading buf[cur]
    const long kn = (long)(it + 2) * 64;
    if (kn < K) {
      #pragma unroll
      for (int i = 0; i < 4; ++i) {
        int c = wid * 4 + i;
        GLDS16(Ab + (long)srcrow[i] * ldA + kn + srcoff[i], lA[cur] + c * 512);
        GLDS16(Wb + (long)srcrow[i] * ldW + kn + srcoff[i], lW[cur] + c * 512);
      }
    }
  }

  #pragma unroll
  for (int ni = 0; ni < 4; ++ni) {
    long col = col0 + wn + ni * 16 + l15;
    float bvv = HASBIAS ? bias[col] : 0.f;
    #pragma unroll
    for (int mi = 0; mi < 4; ++mi) {
      #pragma unroll
      for (int r = 0; r < 4; ++r) {
        long row = row0 + wm + mi * 16 + quad * 4 + r;
        float v = acc[mi][ni][r];
        if (HASBIAS) v += bvv;
        if (RELU)    v = fmaxf(v, 0.f);
        if (HASRES) {
          long ro = (long)z * resZ + row * ldres + col;
          v += RESB ? b2f(((const short*)res)[ro]) : ((const float*)res)[ro];
        }
        outB[(long)z * Cz + row * ldC + col] = f2b(v);
      }
    }
  }
}

// ---------------- per-mode complex GEMM ----------------
__global__ __launch_bounds__(256) void mode_gemm(
    const short* __restrict__ qr, const short* __restrict__ qi,
    const short* __restrict__ wr, const short* __restrict__ wi,
    short* __restrict__ outm)
{
  __shared__ short lqr[16 * 64], lqi[16 * 64], lwr[64 * 64], lwi[64 * 64];
  const int m = blockIdx.x, en = blockIdx.y;
  const int t = threadIdx.x, lane = t & 63, wid = t >> 6;
  const int quad = lane >> 4, l15 = lane & 15;
  const short* qrb = qr + (long)m * (B_ * D_);
  const short* qib = qi + (long)m * (B_ * D_);
  const short* wrb = wr + (long)m * (D_ * D_) + (long)en * 64 * D_;
  const short* wib = wi + (long)m * (D_ * D_) + (long)en * 64 * D_;
  f32x4 accr = zero4(), acci = zero4();
  for (int k0 = 0; k0 < D_; k0 += 64) {
    __syncthreads();
    {
      int idx = t & 127; int r = idx >> 3, cg = idx & 7;
      const short* src = (t < 128 ? qrb : qib) + r * D_ + k0 + cg * 8;
      short* dst = (t < 128) ? lqr : lqi;
      *(short8*)&dst[SWZ(r, cg)] = *(const short8*)src;
    }
    #pragma unroll
    for (int i = 0; i < 4; ++i) {
      int idx = i * 256 + t;
      int which = idx >> 9, idx2 = idx & 511;
      int r = idx2 >> 3, cg = idx2 & 7;
      const short* src = (which ? wib : wrb) + r * D_ + k0 + cg * 8;
      short* dst = which ? lwi : lwr;
      *(short8*)&dst[SWZ(r, cg)] = *(const short8*)src;
    }
    __syncthreads();
    #pragma unroll
    for (int ks = 0; ks < 2; ++ks) {
      int gq = ks * 4 + quad;
      short8 ar = *(const short8*)&lqr[SWZ(l15, gq)];
      short8 ai = *(const short8*)&lqi[SWZ(l15, gq)];
      short8 br = *(const short8*)&lwr[SWZ(wid * 16 + l15, gq)];
      short8 bi = *(const short8*)&lwi[SWZ(wid * 16 + l15, gq)];
      short8 nai;
      #pragma unroll
      for (int j = 0; j < 8; ++j) nai[j] = (short)(ai[j] ^ (short)0x8000);
      accr = MFMA(ar, br, accr);
      accr = MFMA(nai, bi, accr);   // - qi*wi
      acci = MFMA(ar, bi, acci);
      acci = MFMA(ai, br, acci);
    }
  }
  #pragma unroll
  for (int r = 0; r < 4; ++r) {
    int bb = quad * 4 + r;
    long e = (long)en * 64 + wid * 16 + l15;
    long base = ((long)bb * D_ + e) * 128 + m;
    outm[base]      = f2b(accr[r]);
    outm[base + 64] = f2b(acci[r]);
  }
}

// ---------------- fused gates + seasonal combine ----------------
// Per block (lc,b): compute softmax gates for its 64 positions from H (wave-
// shuffle reduce, same math as the old gates_kernel), then
// out = x - sum_e gate_e * avgpool_{3,5,7}(x).
template<bool OUTF, bool WRITEB>
__global__ __launch_bounds__(512) void combine_kernel(
    const short* __restrict__ xin, const short* __restrict__ h,
    const float* __restrict__ w2, const float* __restrict__ b2,
    float* __restrict__ outf, short* __restrict__ outb)
{
  __shared__ float lG[64][4];
  int lc = blockIdx.x, b = blockIdx.y, t = threadIdx.x;
  int wid = t >> 6, lane = t & 63;
  int l0 = lc * 64;
  // gates: 8 positions per wave
  #pragma unroll
  for (int pi = 0; pi < 8; ++pi) {
    int pos = wid * 8 + pi;
    long row = (long)b * L_ + l0 + pos;
    short4v hh = *(const short4v*)(h + row * HID + lane * 4);
    float hv[4];
    #pragma unroll
    for (int j = 0; j < 4; ++j) hv[j] = b2f(hh[j]);
    float lg[3];
    #pragma unroll
    for (int e = 0; e < 3; ++e) {
      const float* wrow = w2 + e * HID + lane * 4;
      float p = hv[0] * wrow[0] + hv[1] * wrow[1] + hv[2] * wrow[2] + hv[3] * wrow[3];
      #pragma unroll
      for (int off = 32; off >= 1; off >>= 1) p += __shfl_xor(p, off);
      lg[e] = p + b2[e];
    }
    float mx = fmaxf(lg[0], fmaxf(lg[1], lg[2]));
    float e0 = __expf(lg[0] - mx), e1 = __expf(lg[1] - mx), e2 = __expf(lg[2] - mx);
    float inv = 1.f / (e0 + e1 + e2);
    float gv = (lane == 0) ? e0 * inv : (lane == 1) ? e1 * inv : e2 * inv;
    if (lane < 3) lG[pos][lane] = gv;
  }
  __syncthreads();

  int d = t;  // 512 threads = D
  const short* xb = xin + (long)b * L_ * D_ + d;
  float win[7];
  #pragma unroll
  for (int j = 0; j < 6; ++j) {
    int l = l0 - 3 + j;
    win[j] = (l >= 0 && l < L_) ? b2f(xb[(long)l * D_]) : 0.f;
  }
  for (int i = 0; i < 64; ++i) {
    int lcn = l0 + i;
    int lr = lcn + 3;
    win[6] = (lr < L_) ? b2f(xb[(long)lr * D_]) : 0.f;
    float s3 = win[2] + win[3] + win[4];
    float s5 = s3 + win[1] + win[5];
    float s7 = s5 + win[0] + win[6];
    float trend = lG[i][0] * s3 * (1.f / 3.f) + lG[i][1] * s5 * (1.f / 5.f)
                + lG[i][2] * s7 * (1.f / 7.f);
    float v = win[3] - trend;
    long o = ((long)b * L_ + lcn) * D_ + d;
    if (OUTF)   outf[o] = v;
    if (WRITEB) outb[o] = f2b(v);
    #pragma unroll
    for (int j = 0; j < 6; ++j) win[j] = win[j + 1];
  }
}

extern "C" void kernel_launch(void* const* d_in, const int* in_sizes, int n_in,
                              void* d_out, int out_size, void* d_ws, size_t ws_size,
                              hipStream_t stream) {
  const float* x       = (const float*)d_in[0];
  const float* w_real  = (const float*)d_in[1];
  const float* w_imag  = (const float*)d_in[2];
  const float* conv1_w = (const float*)d_in[3];
  const float* conv2_w = (const float*)d_in[4];
  const float* d1_w1   = (const float*)d_in[5];
  const float* d1_b1   = (const float*)d_in[6];
  const float* d1_w2   = (const float*)d_in[7];
  const float* d1_b2   = (const float*)d_in[8];
  const float* d2_w1   = (const float*)d_in[9];
  const float* d2_b1   = (const float*)d_in[10];
  const float* d2_w2   = (const float*)d_in[11];
  const float* d2_b2   = (const float*)d_in[12];
  float* OUT = (float*)d_out;

  // BIG (ws >= 144,703,488): full-M FFN (confirmed taken in R4: FETCH 127 MB).
  // SMALL (ws >= 98,566,144): 2-chunk FFN fallback.
  const size_t REQ_BIG = 144703488, REQ_SMALL = 98566144;
  if (ws_size < REQ_SMALL) {
    zero_out<<<(out_size + 255) / 256, 256, 0, stream>>>(OUT, out_size);
    return;
  }
  const bool big = (ws_size >= REQ_BIG);

  char* ws = (char*)d_ws;
  short* C1WB  = (short*)(ws + 0);          //  2,097,152
  short* C2WB  = (short*)(ws + 2097152);    //  2,097,152
  short* D1W1B = (short*)(ws + 4194304);    //    262,144
  short* D2W1B = (short*)(ws + 4456448);    //    262,144
  short* TCS   = (short*)(ws + 4718592);    //    393,216
  short* BASIS = (short*)(ws + 5111808);    //    393,216 (pad -> 6,291,456)
  short* XT    = (short*)(ws + 6291456);    // 25,165,824 [dead after fwdDFT]
  short* Y1    = XT;                        // big:100.7MB / small:50.3MB [FFN phase]
  short* QRI   = (short*)(ws + 31457280);   //  2,097,152 [written by fwdDFT col-store; dead after modes]
  short* OUTM  = (short*)(ws + 33554432);   //  2,097,152 [dead after invDFT]
  short* WTR   = (short*)(ws + 35651584);   // 33,554,432 [dead after modes]
  short* X1B   = WTR;                       // 25,165,824 [alias; dead after combine1]
  short* WTI   = (short*)(ws + 69206016);   // 33,554,432 [dead after modes]
  short* X2B   = (short*)(ws + (big ? 106954752 : 60817408));   // 25,165,824 (FFN2 in-place)
  short* H     = (short*)(ws + (big ? 132120576 : 85983232));   // 12,582,912

  // --- prep: all converts + DFT tables in ONE dispatch ---
  prep_all<<<3840, 256, 0, stream>>>(conv1_w, conv2_w, d1_w1, d2_w1,
                                     C1WB, C2WB, D1W1B, D2W1B, TCS, BASIS);
  transpose_w<<<dim3(8, 512, 8), 256, 0, stream>>>(w_real, w_imag, WTR, WTI);
  transpose_x<<<dim3(8, 24, 16), 256, 0, stream>>>(x, XT);

  // --- forward DFT with col-major store: QRI[c][bd] directly (csr=1, csc=8192) ---
  gemm64<false, false><<<dim3(128, 2), 256, 0, stream>>>(
      XT, L_, TCS, L_, nullptr, QRI, 1, (long)B_ * D_, L_);

  // --- per-mode complex matmul ---
  mode_gemm<<<dim3(64, 8), 256, 0, stream>>>(QRI, QRI + 64 * B_ * D_, WTR, WTI, OUTM);

  // --- inverse DFT + residual: x1 = x + irfft ---
  gemm128<false, false, true, false><<<dim3(12, 4, 16), 256, 0, stream>>>(
      BASIS, 128, 0, OUTM, 128, (long)D_ * 128, nullptr,
      x, D_, (long)L_ * D_, X1B, D_, (long)L_ * D_, 128);

  // --- decomp 1: H gemm, then fused gates+combine ---
  gemm64<true, true><<<dim3(384, 4), 256, 0, stream>>>(
      X1B, D_, D1W1B, D_, d1_b1, H, HID, 1, D_);
  combine_kernel<false, true><<<dim3(24, 16), 512, 0, stream>>>(
      X1B, H, d1_w2, d1_b2, nullptr, X2B);

  // --- FFN (big: single full-M pass; small: 2 row-chunks). FFN2 in-place into X2B. ---
  {
    const int nchunk = big ? 1 : 2;
    const long rows = big ? 24576 : 12288;
    for (int rc = 0; rc < nchunk; ++rc) {
      short* Ain = X2B + (long)rc * rows * D_;
      gemm128<true, false, false, false><<<dim3(rows / 128, 16, 1), 256, 0, stream>>>(
          Ain, D_, 0, C1WB, D_, 0, nullptr, nullptr, 0, 0, Y1, DFF_, 0, D_);
      gemm128<false, false, true, true><<<dim3(rows / 128, 4, 1), 256, 0, stream>>>(
          Y1, DFF_, 0, C2WB, DFF_, 0, nullptr, Ain, D_, 0, Ain, D_, 0, DFF_);
    }
  }

  // --- decomp 2 -> d_out ---
  gemm64<true, true><<<dim3(384, 4), 256, 0, stream>>>(
      X2B, D_, D2W1B, D_, d2_b1, H, HID, 1, D_);
  combine_kernel<true, false><<<dim3(24, 16), 512, 0, stream>>>(
      X2B, H, d2_w2, d2_b2, OUT, nullptr);
}

// Round 2
// 586.480 us; speedup vs baseline: 1.0759x; 1.0759x over previous
//
#include <hip/hip_runtime.h>

#define B_   16
#define L_   1536
#define D_   512
#define DFF_ 2048
#define NM   64
#define HID  256

typedef short short8  __attribute__((ext_vector_type(8)));
typedef short short4v __attribute__((ext_vector_type(4)));
typedef float f32x4   __attribute__((ext_vector_type(4)));

__device__ __forceinline__ float b2f(short s) {
  unsigned int u = ((unsigned int)(unsigned short)s) << 16;
  float f; __builtin_memcpy(&f, &u, 4); return f;
}
__device__ __forceinline__ short f2b(float f) {
  unsigned int u; __builtin_memcpy(&u, &f, 4);
  u += 0x7fffu + ((u >> 16) & 1u);
  return (short)(u >> 16);
}
__device__ __forceinline__ f32x4 zero4() {
  f32x4 v; v[0]=0.f; v[1]=0.f; v[2]=0.f; v[3]=0.f; return v;
}

#define MFMA(a,b,c) __builtin_amdgcn_mfma_f32_16x16x32_bf16((a),(b),(c),0,0,0)
// XOR-swizzled LDS offset (shorts) for 64-short rows: row*64 + (grp^(row&7))*8
#define SWZ(row, grp) (((row) << 6) + ((((grp) ^ ((row) & 7))) << 3))
// async 16B/lane global->LDS (m97: width 16 => global_load_lds_dwordx4)
#define GLDS16(gp, lp) __builtin_amdgcn_global_load_lds( \
    (const __attribute__((address_space(1))) void*)(gp), \
    (__attribute__((address_space(3))) void*)(lp), 16, 0, 0)
#define MEMFENCE asm volatile("" ::: "memory")

// ---------------- guard: zero output (ws too small diagnostic) ----------------
__global__ __launch_bounds__(256) void zero_out(float* __restrict__ o, int n) {
  int i = blockIdx.x * 256 + threadIdx.x;
  if (i < n) o[i] = 0.f;
}

// ---------------- fused prep: 4x f32->bf16 convert + DFT tables ----------------
__global__ __launch_bounds__(256) void prep_all(
    const float* __restrict__ conv1_w, const float* __restrict__ conv2_w,
    const float* __restrict__ d1_w1,  const float* __restrict__ d2_w1,
    short* __restrict__ c1, short* __restrict__ c2,
    short* __restrict__ dw1, short* __restrict__ dw2,
    short* __restrict__ tcs, short* __restrict__ basis)
{
  int blk = blockIdx.x;
  if (blk < 2304) {   // converts: pick source/dest
    const float* s; short* d; int i;
    if (blk < 1024)      { s = conv1_w; d = c1;  i = blk * 256 + threadIdx.x; }
    else if (blk < 2048) { s = conv2_w; d = c2;  i = (blk - 1024) * 256 + threadIdx.x; }
    else if (blk < 2176) { s = d1_w1;   d = dw1; i = (blk - 2048) * 256 + threadIdx.x; }
    else                 { s = d2_w1;   d = dw2; i = (blk - 2176) * 256 + threadIdx.x; }
    f32x4 v = ((const f32x4*)s)[i];
    short4v o;
    #pragma unroll
    for (int j = 0; j < 4; ++j) o[j] = f2b(v[j]);
    ((short4v*)d)[i] = o;
    return;
  }
  if (blk < 3072) {   // tcs[m][l], m<64: cos; m>=64: -sin
    int i = (blk - 2304) * 256 + threadIdx.x;
    int m = i / L_, l = i - m * L_;
    int mm = (m < 64) ? m : (m - 64);
    int r = (mm * l) % L_;
    float th = (float)r * (6.283185307179586f / (float)L_);
    float s, c; __sincosf(th, &s, &c);
    tcs[i] = f2b((m < 64) ? c : -s);
    return;
  }
  {   // basis[l][k]
    int i = (blk - 3072) * 256 + threadIdx.x;
    int l = i >> 7, k = i & 127;
    int m = (k < 64) ? k : (k - 64);
    int r = (m * l) % L_;
    float th = (float)r * (6.283185307179586f / (float)L_);
    float s, c; __sincosf(th, &s, &c);
    float v = (k < 64) ? ((m == 0) ? 1.f : 2.f) * (1.f / (float)L_) * c
                       : (-2.f / (float)L_) * s;
    basis[i] = f2b(v);
  }
}

// ---------------- w[d][e][m] f32 -> wt[m][e][d] bf16; z<4 real, z>=4 imag ----------------
__global__ __launch_bounds__(256) void transpose_w(
    const float* __restrict__ wre, const float* __restrict__ wim,
    short* __restrict__ wtr, short* __restrict__ wti)
{
  __shared__ float tile[64][17];
  int dc = blockIdx.x, e = blockIdx.y, t = threadIdx.x;
  int zz = blockIdx.z;
  const float* w = (zz < 4) ? wre : wim;
  short* wt      = (zz < 4) ? wtr : wti;
  int mBase = (zz & 3) * 16;
  {
    int dl = t >> 2, mg = t & 3;
    f32x4 v = *(const f32x4*)(w + ((long)(dc * 64 + dl) * 512 + e) * 64 + mBase + mg * 4);
    tile[dl][mg*4+0] = v[0]; tile[dl][mg*4+1] = v[1];
    tile[dl][mg*4+2] = v[2]; tile[dl][mg*4+3] = v[3];
  }
  __syncthreads();
  if (t < 128) {
    int mr = t >> 3, dg = t & 7;
    short8 o;
    #pragma unroll
    for (int j = 0; j < 8; ++j) o[j] = f2b(tile[dg * 8 + j][mr]);
    *(short8*)(wt + ((long)(mBase + mr) * 512 + e) * 512 + dc * 64 + dg * 8) = o;
  }
}

// ---------------- x[b][l][d] f32 -> xt[b][d][l] bf16 ----------------
__global__ __launch_bounds__(256) void transpose_x(const float* __restrict__ x,
                                                   short* __restrict__ xt) {
  __shared__ float tile[64][65];
  int dc = blockIdx.x, lc = blockIdx.y, b = blockIdx.z, t = threadIdx.x;
  const float* xb = x + (long)b * L_ * D_;
  #pragma unroll
  for (int i = 0; i < 4; ++i) {
    int idx = i * 256 + t; int ll = idx >> 4, dg = idx & 15;
    f32x4 v = *(const f32x4*)(xb + (long)(lc * 64 + ll) * D_ + dc * 64 + dg * 4);
    tile[ll][dg*4+0] = v[0]; tile[ll][dg*4+1] = v[1];
    tile[ll][dg*4+2] = v[2]; tile[ll][dg*4+3] = v[3];
  }
  __syncthreads();
  #pragma unroll
  for (int i = 0; i < 2; ++i) {
    int idx = i * 256 + t; int dl = idx >> 3, lg = idx & 7;
    short8 o;
    #pragma unroll
    for (int j = 0; j < 8; ++j) o[j] = f2b(tile[lg * 8 + j][dl]);
    *(short8*)(xt + ((long)b * D_ + dc * 64 + dl) * L_ + lc * 64 + lg * 8) = o;
  }
}

// ---------------- 64x64-tile bf16 MFMA GEMM (dbuf + counted vmcnt) ----------------
template<bool RELU, bool HASBIAS>
__global__ __launch_bounds__(256) void gemm64(
    const short* __restrict__ A, long ldA,
    const short* __restrict__ W, long ldW,
    const float* __restrict__ bias,
    short* __restrict__ outB, long csr, long csc, int K)
{
  __shared__ short lA[2][64 * 64];
  __shared__ short lW[2][64 * 64];
  const int t = threadIdx.x, lane = t & 63, wid = t >> 6;
  const int quad = lane >> 4, l15 = lane & 15;
  const int wm = (wid & 1) * 32, wn = (wid >> 1) * 32;
  const long row0 = (long)blockIdx.x * 64, col0 = (long)blockIdx.y * 64;
  const short* Ab = A + row0 * ldA;
  const short* Wb = W + col0 * ldW;

  int srcrow[2]; long srcoff[2];
  #pragma unroll
  for (int i = 0; i < 2; ++i) {
    int c = wid * 2 + i;
    int r = c * 8 + (lane >> 3);
    int g = (lane & 7) ^ (r & 7);
    srcrow[i] = r; srcoff[i] = g * 8;
  }

  f32x4 acc[2][2];
  #pragma unroll
  for (int i = 0; i < 2; ++i)
    #pragma unroll
    for (int j = 0; j < 2; ++j) acc[i][j] = zero4();

  const int nk = K >> 6;
  #pragma unroll
  for (int i = 0; i < 2; ++i) {
    int c = wid * 2 + i;
    GLDS16(Ab + (long)srcrow[i] * ldA + srcoff[i], lA[0] + c * 512);
    GLDS16(Wb + (long)srcrow[i] * ldW + srcoff[i], lW[0] + c * 512);
  }
  if (nk > 1) {
    #pragma unroll
    for (int i = 0; i < 2; ++i) {
      int c = wid * 2 + i;
      GLDS16(Ab + (long)srcrow[i] * ldA + 64 + srcoff[i], lA[1] + c * 512);
      GLDS16(Wb + (long)srcrow[i] * ldW + 64 + srcoff[i], lW[1] + c * 512);
    }
  }

  for (int it = 0; it < nk; ++it) {
    if (it + 1 < nk) asm volatile("s_waitcnt vmcnt(4)" ::: "memory");
    else             asm volatile("s_waitcnt vmcnt(0)" ::: "memory");
    __builtin_amdgcn_s_barrier();
    const int cur = it & 1;
    const short* bufA = lA[cur];
    const short* bufW = lW[cur];
    #pragma unroll
    for (int ks = 0; ks < 2; ++ks) {
      int gq = ks * 4 + quad;
      short8 a0 = *(const short8*)&bufA[SWZ(wm + l15, gq)];
      short8 a1 = *(const short8*)&bufA[SWZ(wm + 16 + l15, gq)];
      short8 b0 = *(const short8*)&bufW[SWZ(wn + l15, gq)];
      short8 b1 = *(const short8*)&bufW[SWZ(wn + 16 + l15, gq)];
      acc[0][0] = MFMA(a0, b0, acc[0][0]);
      acc[0][1] = MFMA(a0, b1, acc[0][1]);
      acc[1][0] = MFMA(a1, b0, acc[1][0]);
      acc[1][1] = MFMA(a1, b1, acc[1][1]);
    }
    asm volatile("s_waitcnt lgkmcnt(0)" ::: "memory");
    __builtin_amdgcn_s_barrier();
    const long kn = (long)(it + 2) * 64;
    if (kn < K) {
      #pragma unroll
      for (int i = 0; i < 2; ++i) {
        int c = wid * 2 + i;
        GLDS16(Ab + (long)srcrow[i] * ldA + kn + srcoff[i], lA[cur] + c * 512);
        GLDS16(Wb + (long)srcrow[i] * ldW + kn + srcoff[i], lW[cur] + c * 512);
      }
    }
  }

  #pragma unroll
  for (int ni = 0; ni < 2; ++ni) {
    long col = col0 + wn + ni * 16 + l15;
    float bvv = HASBIAS ? bias[col] : 0.f;
    #pragma unroll
    for (int mi = 0; mi < 2; ++mi) {
      #pragma unroll
      for (int r = 0; r < 4; ++r) {
        long row = row0 + wm + mi * 16 + quad * 4 + r;
        float v = acc[mi][ni][r];
        if (HASBIAS) v += bvv;
        if (RELU)    v = fmaxf(v, 0.f);
        outB[row * csr + col * csc] = f2b(v);
      }
    }
  }
}

// ---------------- 128x128-tile bf16 MFMA GEMM (dbuf + counted vmcnt) ----------------
template<bool RELU, bool HASBIAS, bool HASRES, bool RESB>
__global__ __launch_bounds__(256) void gemm128(
    const short* __restrict__ A, long ldA, long Az,
    const short* __restrict__ W, long ldW, long Wz,
    const float* __restrict__ bias,
    const void* __restrict__ res, long ldres, long resZ,
    short* __restrict__ outB, long ldC, long Cz, int K)
{
  __shared__ short lA[2][128 * 64];
  __shared__ short lW[2][128 * 64];
  const int t = threadIdx.x, lane = t & 63, wid = t >> 6;
  const int quad = lane >> 4, l15 = lane & 15;
  const int wm = (wid & 1) * 64, wn = (wid >> 1) * 64;
  const long row0 = (long)blockIdx.x * 128, col0 = (long)blockIdx.y * 128;
  const int z = blockIdx.z;
  const short* Ab = A + (long)z * Az + row0 * ldA;
  const short* Wb = W + (long)z * Wz + col0 * ldW;

  int srcrow[4]; long srcoff[4];
  #pragma unroll
  for (int i = 0; i < 4; ++i) {
    int c = wid * 4 + i;
    int r = c * 8 + (lane >> 3);
    int g = (lane & 7) ^ (r & 7);
    srcrow[i] = r; srcoff[i] = g * 8;
  }

  f32x4 acc[4][4];
  #pragma unroll
  for (int i = 0; i < 4; ++i)
    #pragma unroll
    for (int j = 0; j < 4; ++j) acc[i][j] = zero4();

  const int nk = K >> 6;
  #pragma unroll
  for (int i = 0; i < 4; ++i) {
    int c = wid * 4 + i;
    GLDS16(Ab + (long)srcrow[i] * ldA + srcoff[i], lA[0] + c * 512);
    GLDS16(Wb + (long)srcrow[i] * ldW + srcoff[i], lW[0] + c * 512);
  }
  if (nk > 1) {
    #pragma unroll
    for (int i = 0; i < 4; ++i) {
      int c = wid * 4 + i;
      GLDS16(Ab + (long)srcrow[i] * ldA + 64 + srcoff[i], lA[1] + c * 512);
      GLDS16(Wb + (long)srcrow[i] * ldW + 64 + srcoff[i], lW[1] + c * 512);
    }
  }

  for (int it = 0; it < nk; ++it) {
    if (it + 1 < nk) asm volatile("s_waitcnt vmcnt(8)" ::: "memory");
    else             asm volatile("s_waitcnt vmcnt(0)" ::: "memory");
    __builtin_amdgcn_s_barrier();
    const int cur = it & 1;
    const short* bufA = lA[cur];
    const short* bufW = lW[cur];
    #pragma unroll
    for (int ks = 0; ks < 2; ++ks) {
      int gq = ks * 4 + quad;
      short8 av[4], bv[4];
      #pragma unroll
      for (int mi = 0; mi < 4; ++mi) av[mi] = *(const short8*)&bufA[SWZ(wm + mi * 16 + l15, gq)];
      #pragma unroll
      for (int ni = 0; ni < 4; ++ni) bv[ni] = *(const short8*)&bufW[SWZ(wn + ni * 16 + l15, gq)];
      #pragma unroll
      for (int mi = 0; mi < 4; ++mi)
        #pragma unroll
        for (int ni = 0; ni < 4; ++ni)
          acc[mi][ni] = MFMA(av[mi], bv[ni], acc[mi][ni]);
    }
    asm volatile("s_waitcnt lgkmcnt(0)" ::: "memory");
    __builtin_amdgcn_s_barrier();
    const long kn = (long)(it + 2) * 64;
    if (kn < K) {
      #pragma unroll
      for (int i = 0; i < 4; ++i) {
        int c = wid * 4 + i;
        GLDS16(Ab + (long)srcrow[i] * ldA + kn + srcoff[i], lA[cur] + c * 512);
        GLDS16(Wb + (long)srcrow[i] * ldW + kn + srcoff[i], lW[cur] + c * 512);
      }
    }
  }

  #pragma unroll
  for (int ni = 0; ni < 4; ++ni) {
    long col = col0 + wn + ni * 16 + l15;
    float bvv = HASBIAS ? bias[col] : 0.f;
    #pragma unroll
    for (int mi = 0; mi < 4; ++mi) {
      #pragma unroll
      for (int r = 0; r < 4; ++r) {
        long row = row0 + wm + mi * 16 + quad * 4 + r;
        float v = acc[mi][ni][r];
        if (HASBIAS) v += bvv;
        if (RELU)    v = fmaxf(v, 0.f);
        if (HASRES) {
          long ro = (long)z * resZ + row * ldres + col;
          v += RESB ? b2f(((const short*)res)[ro]) : ((const float*)res)[ro];
        }
        outB[(long)z * Cz + row * ldC + col] = f2b(v);
      }
    }
  }
}

// ---------------- 256x256-tile 8-phase bf16 MFMA GEMM (T1+T2+T3+T4+T5) ----------------
// 512 threads = 8 waves (2M x 4N); per-wave 128x64 output; BK=64, iteration = 2 K-tiles.
// LDS 128 KiB: A[tp][half][128][64] + B[tp][half][128][64], tp = K-tile parity.
// Per phase: {12 ds_read_b128 | barrier | lgkm(0) | setprio(1) 16 MFMA setprio(0) | barrier}.
// Staging: 8 GLDS16 burst at phases 0 (odd slots <- tile 2i+1) and 4 (even <- 2i+2);
// vmcnt(8) counted waits only at those two points (4-phase prefetch lead), vmcnt(0)
// only at the final K-tile. Requires K % 128 == 0, M,N % 256 == 0, grid % 8 == 0.
template<bool RELU, bool HASRES>
__global__ __launch_bounds__(512, 2) void gemm256(
    const short* __restrict__ A, long ldA,
    const short* __restrict__ W, long ldW,
    const short* __restrict__ res, long ldres,
    short* __restrict__ outB, long ldC, int K, int gn)
{
  __shared__ short sh[65536];           // 128 KiB: A at 0, B at 32768 (shorts)
  const int t = threadIdx.x;
  const int lane = t & 63, wid = t >> 6;
  const int quad = lane >> 4, l15 = lane & 15;
  const int wr = wid >> 2, wc = wid & 3;
  const int wch = wc >> 1, cbw = (wc & 1) * 64;

  // XCD-aware bijective swizzle (grid % 8 == 0 guaranteed by caller)
  const int nwg = gridDim.x;
  const int cpx = nwg >> 3;
  const int wg = (blockIdx.x & 7) * cpx + (blockIdx.x >> 3);
  const int bx = wg / gn, by = wg - bx * gn;
  const long row0 = (long)bx * 256, col0 = (long)by * 256;

  const short* Ab = A + row0 * ldA;
  const short* Wb = W + col0 * ldW;

  // staging geometry: thread t covers 16B chunk (j*512+t) of each half-tile;
  // source k-group pre-swizzled so linear LDS write + SWZ read match (involution).
  const int srw = t >> 3;                 // row-within-64 block
  const int sg  = (t & 7) ^ (srw & 7);    // pre-swizzled k-group

#define STAGE(TP, KB) do {                                                   \
    const long ko_ = (long)(KB) + sg * 8;                                    \
    _Pragma("unroll")                                                        \
    for (int h_ = 0; h_ < 2; ++h_) {                                         \
      short* dA_ = sh + ((TP) * 2 + h_) * 8192;                              \
      short* dB_ = sh + 32768 + ((TP) * 2 + h_) * 8192;                      \
      _Pragma("unroll")                                                      \
      for (int j_ = 0; j_ < 2; ++j_) {                                       \
        const long gr_ = (long)(h_ * 128 + srw + j_ * 64);                   \
        GLDS16(Ab + gr_ * ldA + ko_, dA_ + (j_ * 512 + t) * 8);              \
        GLDS16(Wb + gr_ * ldW + ko_, dB_ + (j_ * 512 + t) * 8);              \
      }                                                                      \
    }                                                                        \
  } while (0)

  f32x4 acc[8][4];
  #pragma unroll
  for (int i = 0; i < 8; ++i)
    #pragma unroll
    for (int j = 0; j < 4; ++j) acc[i][j] = zero4();

#define PH_LOADS(TP, QM, QN)                                                 \
    const short* aS_ = sh + ((TP) * 2 + wr) * 8192;                          \
    const short* bS_ = sh + 32768 + ((TP) * 2 + wch) * 8192;                 \
    short8 av[4][2], bv[2][2];                                               \
    _Pragma("unroll")                                                        \
    for (int u = 0; u < 4; ++u)                                              \
      _Pragma("unroll")                                                      \
      for (int ks = 0; ks < 2; ++ks)                                         \
        av[u][ks] = *(const short8*)&aS_[SWZ(((QM)*4+u)*16 + l15, ks*4 + quad)]; \
    _Pragma("unroll")                                                        \
    for (int v = 0; v < 2; ++v)                                              \
      _Pragma("unroll")                                                      \
      for (int ks = 0; ks < 2; ++ks)                                         \
        bv[v][ks] = *(const short8*)&bS_[SWZ(cbw + ((QN)*2+v)*16 + l15, ks*4 + quad)];

#define PH_MMA(QM, QN) do {                                                  \
    asm volatile("s_waitcnt lgkmcnt(0)" ::: "memory");                       \
    __builtin_amdgcn_s_setprio(1);                                           \
    _Pragma("unroll")                                                        \
    for (int ks = 0; ks < 2; ++ks)                                           \
      _Pragma("unroll")                                                      \
      for (int u = 0; u < 4; ++u)                                            \
        _Pragma("unroll")                                                    \
        for (int v = 0; v < 2; ++v)                                          \
          acc[(QM)*4+u][(QN)*2+v] =                                          \
              MFMA(av[u][ks], bv[v][ks], acc[(QM)*4+u][(QN)*2+v]);           \
    __builtin_amdgcn_s_setprio(0);                                           \
  } while (0)

  // lead phase: barrier already passed by caller; loads AFTER barrier
#define PH_LEAD(TP, QM, QN) do {                                             \
    PH_LOADS(TP, QM, QN);                                                    \
    PH_MMA(QM, QN);                                                          \
    MEMFENCE; __builtin_amdgcn_s_barrier(); MEMFENCE;                        \
  } while (0)

  // mid phase: loads BEFORE own leading barrier (slots validated earlier)
#define PH_MID(TP, QM, QN) do {                                              \
    PH_LOADS(TP, QM, QN);                                                    \
    MEMFENCE; __builtin_amdgcn_s_barrier();                                  \
    PH_MMA(QM, QN);                                                          \
    MEMFENCE; __builtin_amdgcn_s_barrier(); MEMFENCE;                        \
  } while (0)

  const int NI = K >> 7;   // iterations of 2 K-tiles
  STAGE(0, 0);             // prologue: tile 0 -> even slots

  for (int i = 0; i < NI; ++i) {
    const int kb = i << 7;
    // ---- phase 0: stage tile 2i+1 -> odd slots; first read of tile 2i ----
    STAGE(1, kb + 64);
    asm volatile("s_waitcnt vmcnt(8)" ::: "memory");
    __builtin_amdgcn_s_barrier(); MEMFENCE;
    PH_LEAD(0, 0, 0);
    PH_MID(0, 1, 0);
    PH_MID(0, 0, 1);
    PH_MID(0, 1, 1);
    // ---- phase 4: stage tile 2i+2 -> even slots; first read of tile 2i+1 ----
    if (i + 1 < NI) {
      STAGE(0, kb + 128);
      asm volatile("s_waitcnt vmcnt(8)" ::: "memory");
    } else {
      asm volatile("s_waitcnt vmcnt(0)" ::: "memory");
    }
    __builtin_amdgcn_s_barrier(); MEMFENCE;
    PH_LEAD(1, 0, 0);
    PH_MID(1, 1, 0);
    PH_MID(1, 0, 1);
    PH_MID(1, 1, 1);
  }

  // ---- epilogue: scalar stores (same pattern as gemm128) ----
  #pragma unroll
  for (int ni = 0; ni < 4; ++ni) {
    long col = col0 + wc * 64 + ni * 16 + l15;
    #pragma unroll
    for (int mi = 0; mi < 8; ++mi) {
      #pragma unroll
      for (int r = 0; r < 4; ++r) {
        long row = row0 + wr * 128 + mi * 16 + quad * 4 + r;
        float v = acc[mi][ni][r];
        if (RELU) v = fmaxf(v, 0.f);
        if (HASRES) v += b2f(res[row * ldres + col]);
        outB[row * ldC + col] = f2b(v);
      }
    }
  }
#undef STAGE
#undef PH_LOADS
#undef PH_MMA
#undef PH_LEAD
#undef PH_MID
}

// ---------------- per-mode complex GEMM ----------------
__global__ __launch_bounds__(256) void mode_gemm(
    const short* __restrict__ qr, const short* __restrict__ qi,
    const short* __restrict__ wr, const short* __restrict__ wi,
    short* __restrict__ outm)
{
  __shared__ short lqr[16 * 64], lqi[16 * 64], lwr[64 * 64], lwi[64 * 64];
  const int m = blockIdx.x, en = blockIdx.y;
  const int t = threadIdx.x, lane = t & 63, wid = t >> 6;
  const int quad = lane >> 4, l15 = lane & 15;
  const short* qrb = qr + (long)m * (B_ * D_);
  const short* qib = qi + (long)m * (B_ * D_);
  const short* wrb = wr + (long)m * (D_ * D_) + (long)en * 64 * D_;
  const short* wib = wi + (long)m * (D_ * D_) + (long)en * 64 * D_;
  f32x4 accr = zero4(), acci = zero4();
  for (int k0 = 0; k0 < D_; k0 += 64) {
    __syncthreads();
    {
      int idx = t & 127; int r = idx >> 3, cg = idx & 7;
      const short* src = (t < 128 ? qrb : qib) + r * D_ + k0 + cg * 8;
      short* dst = (t < 128) ? lqr : lqi;
      *(short8*)&dst[SWZ(r, cg)] = *(const short8*)src;
    }
    #pragma unroll
    for (int i = 0; i < 4; ++i) {
      int idx = i * 256 + t;
      int which = idx >> 9, idx2 = idx & 511;
      int r = idx2 >> 3, cg = idx2 & 7;
      const short* src = (which ? wib : wrb) + r * D_ + k0 + cg * 8;
      short* dst = which ? lwi : lwr;
      *(short8*)&dst[SWZ(r, cg)] = *(const short8*)src;
    }
    __syncthreads();
    #pragma unroll
    for (int ks = 0; ks < 2; ++ks) {
      int gq = ks * 4 + quad;
      short8 ar = *(const short8*)&lqr[SWZ(l15, gq)];
      short8 ai = *(const short8*)&lqi[SWZ(l15, gq)];
      short8 br = *(const short8*)&lwr[SWZ(wid * 16 + l15, gq)];
      short8 bi = *(const short8*)&lwi[SWZ(wid * 16 + l15, gq)];
      short8 nai;
      #pragma unroll
      for (int j = 0; j < 8; ++j) nai[j] = (short)(ai[j] ^ (short)0x8000);
      accr = MFMA(ar, br, accr);
      accr = MFMA(nai, bi, accr);   // - qi*wi
      acci = MFMA(ar, bi, acci);
      acci = MFMA(ai, br, acci);
    }
  }
  #pragma unroll
  for (int r = 0; r < 4; ++r) {
    int bb = quad * 4 + r;
    long e = (long)en * 64 + wid * 16 + l15;
    long base = ((long)bb * D_ + e) * 128 + m;
    outm[base]      = f2b(accr[r]);
    outm[base + 64] = f2b(acci[r]);
  }
}

// ---------------- fused gates + seasonal combine ----------------
template<bool OUTF, bool WRITEB>
__global__ __launch_bounds__(512) void combine_kernel(
    const short* __restrict__ xin, const short* __restrict__ h,
    const float* __restrict__ w2, const float* __restrict__ b2,
    float* __restrict__ outf, short* __restrict__ outb)
{
  __shared__ float lG[64][4];
  int lc = blockIdx.x, b = blockIdx.y, t = threadIdx.x;
  int wid = t >> 6, lane = t & 63;
  int l0 = lc * 64;
  #pragma unroll
  for (int pi = 0; pi < 8; ++pi) {
    int pos = wid * 8 + pi;
    long row = (long)b * L_ + l0 + pos;
    short4v hh = *(const short4v*)(h + row * HID + lane * 4);
    float hv[4];
    #pragma unroll
    for (int j = 0; j < 4; ++j) hv[j] = b2f(hh[j]);
    float lg[3];
    #pragma unroll
    for (int e = 0; e < 3; ++e) {
      const float* wrow = w2 + e * HID + lane * 4;
      float p = hv[0] * wrow[0] + hv[1] * wrow[1] + hv[2] * wrow[2] + hv[3] * wrow[3];
      #pragma unroll
      for (int off = 32; off >= 1; off >>= 1) p += __shfl_xor(p, off);
      lg[e] = p + b2[e];
    }
    float mx = fmaxf(lg[0], fmaxf(lg[1], lg[2]));
    float e0 = __expf(lg[0] - mx), e1 = __expf(lg[1] - mx), e2 = __expf(lg[2] - mx);
    float inv = 1.f / (e0 + e1 + e2);
    float gv = (lane == 0) ? e0 * inv : (lane == 1) ? e1 * inv : e2 * inv;
    if (lane < 3) lG[pos][lane] = gv;
  }
  __syncthreads();

  int d = t;  // 512 threads = D
  const short* xb = xin + (long)b * L_ * D_ + d;
  float win[7];
  #pragma unroll
  for (int j = 0; j < 6; ++j) {
    int l = l0 - 3 + j;
    win[j] = (l >= 0 && l < L_) ? b2f(xb[(long)l * D_]) : 0.f;
  }
  for (int i = 0; i < 64; ++i) {
    int lcn = l0 + i;
    int lr = lcn + 3;
    win[6] = (lr < L_) ? b2f(xb[(long)lr * D_]) : 0.f;
    float s3 = win[2] + win[3] + win[4];
    float s5 = s3 + win[1] + win[5];
    float s7 = s5 + win[0] + win[6];
    float trend = lG[i][0] * s3 * (1.f / 3.f) + lG[i][1] * s5 * (1.f / 5.f)
                + lG[i][2] * s7 * (1.f / 7.f);
    float v = win[3] - trend;
    long o = ((long)b * L_ + lcn) * D_ + d;
    if (OUTF)   outf[o] = v;
    if (WRITEB) outb[o] = f2b(v);
    #pragma unroll
    for (int j = 0; j < 6; ++j) win[j] = win[j + 1];
  }
}

extern "C" void kernel_launch(void* const* d_in, const int* in_sizes, int n_in,
                              void* d_out, int out_size, void* d_ws, size_t ws_size,
                              hipStream_t stream) {
  const float* x       = (const float*)d_in[0];
  const float* w_real  = (const float*)d_in[1];
  const float* w_imag  = (const float*)d_in[2];
  const float* conv1_w = (const float*)d_in[3];
  const float* conv2_w = (const float*)d_in[4];
  const float* d1_w1   = (const float*)d_in[5];
  const float* d1_b1   = (const float*)d_in[6];
  const float* d1_w2   = (const float*)d_in[7];
  const float* d1_b2   = (const float*)d_in[8];
  const float* d2_w1   = (const float*)d_in[9];
  const float* d2_b1   = (const float*)d_in[10];
  const float* d2_w2   = (const float*)d_in[11];
  const float* d2_b2   = (const float*)d_in[12];
  float* OUT = (float*)d_out;

  const size_t REQ_BIG = 144703488, REQ_SMALL = 98566144;
  if (ws_size < REQ_SMALL) {
    zero_out<<<(out_size + 255) / 256, 256, 0, stream>>>(OUT, out_size);
    return;
  }
  const bool big = (ws_size >= REQ_BIG);

  char* ws = (char*)d_ws;
  short* C1WB  = (short*)(ws + 0);          //  2,097,152
  short* C2WB  = (short*)(ws + 2097152);    //  2,097,152
  short* D1W1B = (short*)(ws + 4194304);    //    262,144
  short* D2W1B = (short*)(ws + 4456448);    //    262,144
  short* TCS   = (short*)(ws + 4718592);    //    393,216
  short* BASIS = (short*)(ws + 5111808);    //    393,216 (pad -> 6,291,456)
  short* XT    = (short*)(ws + 6291456);    // 25,165,824 [dead after fwdDFT]
  short* Y1    = XT;                        // big:100.7MB / small:50.3MB [FFN phase]
  short* QRI   = (short*)(ws + 31457280);   //  2,097,152
  short* OUTM  = (short*)(ws + 33554432);   //  2,097,152
  short* WTR   = (short*)(ws + 35651584);   // 33,554,432 [dead after modes]
  short* X1B   = WTR;                       // 25,165,824 [alias]
  short* WTI   = (short*)(ws + 69206016);   // 33,554,432 [dead after modes]
  short* X2B   = (short*)(ws + (big ? 106954752 : 60817408));   // 25,165,824
  short* H     = (short*)(ws + (big ? 132120576 : 85983232));   // 12,582,912

  prep_all<<<3840, 256, 0, stream>>>(conv1_w, conv2_w, d1_w1, d2_w1,
                                     C1WB, C2WB, D1W1B, D2W1B, TCS, BASIS);
  transpose_w<<<dim3(8, 512, 8), 256, 0, stream>>>(w_real, w_imag, WTR, WTI);
  transpose_x<<<dim3(8, 24, 16), 256, 0, stream>>>(x, XT);

  gemm64<false, false><<<dim3(128, 2), 256, 0, stream>>>(
      XT, L_, TCS, L_, nullptr, QRI, 1, (long)B_ * D_, L_);

  mode_gemm<<<dim3(64, 8), 256, 0, stream>>>(QRI, QRI + 64 * B_ * D_, WTR, WTI, OUTM);

  gemm128<false, false, true, false><<<dim3(12, 4, 16), 256, 0, stream>>>(
      BASIS, 128, 0, OUTM, 128, (long)D_ * 128, nullptr,
      x, D_, (long)L_ * D_, X1B, D_, (long)L_ * D_, 128);

  gemm64<true, true><<<dim3(384, 4), 256, 0, stream>>>(
      X1B, D_, D1W1B, D_, d1_b1, H, HID, 1, D_);
  combine_kernel<false, true><<<dim3(24, 16), 512, 0, stream>>>(
      X1B, H, d1_w2, d1_b2, nullptr, X2B);

  // --- FFN via 256^2 8-phase GEMM (big: single full-M pass; small: 2 chunks) ---
  {
    const int nchunk = big ? 1 : 2;
    const long rows = big ? 24576 : 12288;
    const int gm = (int)(rows / 256);
    for (int rc = 0; rc < nchunk; ++rc) {
      short* Ain = X2B + (long)rc * rows * D_;
      gemm256<true, false><<<dim3(gm * (DFF_ / 256)), 512, 0, stream>>>(
          Ain, D_, C1WB, D_, nullptr, 0, Y1, DFF_, D_, DFF_ / 256);
      gemm256<false, true><<<dim3(gm * (D_ / 256)), 512, 0, stream>>>(
          Y1, DFF_, C2WB, DFF_, Ain, D_, Ain, D_, DFF_, D_ / 256);
    }
  }

  gemm64<true, true><<<dim3(384, 4), 256, 0, stream>>>(
      X2B, D_, D2W1B, D_, d2_b1, H, HID, 1, D_);
  combine_kernel<true, false><<<dim3(24, 16), 512, 0, stream>>>(
      X2B, H, d2_w2, d2_b2, OUT, nullptr);
}

// Round 3
// 582.921 us; speedup vs baseline: 1.0825x; 1.0061x over previous
//
#include <hip/hip_runtime.h>

#define B_   16
#define L_   1536
#define D_   512
#define DFF_ 2048
#define NM   64
#define HID  256

typedef short short8  __attribute__((ext_vector_type(8)));
typedef short short4v __attribute__((ext_vector_type(4)));
typedef float f32x4   __attribute__((ext_vector_type(4)));

__device__ __forceinline__ float b2f(short s) {
  unsigned int u = ((unsigned int)(unsigned short)s) << 16;
  float f; __builtin_memcpy(&f, &u, 4); return f;
}
__device__ __forceinline__ short f2b(float f) {
  unsigned int u; __builtin_memcpy(&u, &f, 4);
  u += 0x7fffu + ((u >> 16) & 1u);
  return (short)(u >> 16);
}
__device__ __forceinline__ f32x4 zero4() {
  f32x4 v; v[0]=0.f; v[1]=0.f; v[2]=0.f; v[3]=0.f; return v;
}

#define MFMA(a,b,c) __builtin_amdgcn_mfma_f32_16x16x32_bf16((a),(b),(c),0,0,0)
// XOR-swizzled LDS offset (shorts) for 64-short rows: row*64 + (grp^(row&7))*8
#define SWZ(row, grp) (((row) << 6) + ((((grp) ^ ((row) & 7))) << 3))
// async 16B/lane global->LDS (m97: width 16 => global_load_lds_dwordx4)
#define GLDS16(gp, lp) __builtin_amdgcn_global_load_lds( \
    (const __attribute__((address_space(1))) void*)(gp), \
    (__attribute__((address_space(3))) void*)(lp), 16, 0, 0)
#define MEMFENCE asm volatile("" ::: "memory")

// LDS byte address (AS3 offset) of a __shared__ pointer
__device__ __forceinline__ unsigned ldsaddr(const void* p) {
  return (unsigned)(unsigned long long)(const __attribute__((address_space(3))) void*)p;
}
// inline-asm ds_read_b128: opaque to alias analysis -> no compiler-inserted
// vmcnt(0) ordering vs global_load_lds; we count waits manually.
__device__ __forceinline__ short8 dsr128(unsigned a) {
  short8 r;
  asm volatile("ds_read_b128 %0, %1" : "=v"(r) : "v"(a));
  return r;
}

// ---------------- guard: zero output (ws too small diagnostic) ----------------
__global__ __launch_bounds__(256) void zero_out(float* __restrict__ o, int n) {
  int i = blockIdx.x * 256 + threadIdx.x;
  if (i < n) o[i] = 0.f;
}

// ---------------- fused prep: 4x f32->bf16 convert + DFT tables ----------------
__global__ __launch_bounds__(256) void prep_all(
    const float* __restrict__ conv1_w, const float* __restrict__ conv2_w,
    const float* __restrict__ d1_w1,  const float* __restrict__ d2_w1,
    short* __restrict__ c1, short* __restrict__ c2,
    short* __restrict__ dw1, short* __restrict__ dw2,
    short* __restrict__ tcs, short* __restrict__ basis)
{
  int blk = blockIdx.x;
  if (blk < 2304) {   // converts: pick source/dest
    const float* s; short* d; int i;
    if (blk < 1024)      { s = conv1_w; d = c1;  i = blk * 256 + threadIdx.x; }
    else if (blk < 2048) { s = conv2_w; d = c2;  i = (blk - 1024) * 256 + threadIdx.x; }
    else if (blk < 2176) { s = d1_w1;   d = dw1; i = (blk - 2048) * 256 + threadIdx.x; }
    else                 { s = d2_w1;   d = dw2; i = (blk - 2176) * 256 + threadIdx.x; }
    f32x4 v = ((const f32x4*)s)[i];
    short4v o;
    #pragma unroll
    for (int j = 0; j < 4; ++j) o[j] = f2b(v[j]);
    ((short4v*)d)[i] = o;
    return;
  }
  if (blk < 3072) {   // tcs[m][l], m<64: cos; m>=64: -sin
    int i = (blk - 2304) * 256 + threadIdx.x;
    int m = i / L_, l = i - m * L_;
    int mm = (m < 64) ? m : (m - 64);
    int r = (mm * l) % L_;
    float th = (float)r * (6.283185307179586f / (float)L_);
    float s, c; __sincosf(th, &s, &c);
    tcs[i] = f2b((m < 64) ? c : -s);
    return;
  }
  {   // basis[l][k]
    int i = (blk - 3072) * 256 + threadIdx.x;
    int l = i >> 7, k = i & 127;
    int m = (k < 64) ? k : (k - 64);
    int r = (m * l) % L_;
    float th = (float)r * (6.283185307179586f / (float)L_);
    float s, c; __sincosf(th, &s, &c);
    float v = (k < 64) ? ((m == 0) ? 1.f : 2.f) * (1.f / (float)L_) * c
                       : (-2.f / (float)L_) * s;
    basis[i] = f2b(v);
  }
}

// ---------------- w[d][e][m] f32 -> wt[m][e][d] bf16; z<4 real, z>=4 imag ----------------
__global__ __launch_bounds__(256) void transpose_w(
    const float* __restrict__ wre, const float* __restrict__ wim,
    short* __restrict__ wtr, short* __restrict__ wti)
{
  __shared__ float tile[64][17];
  int dc = blockIdx.x, e = blockIdx.y, t = threadIdx.x;
  int zz = blockIdx.z;
  const float* w = (zz < 4) ? wre : wim;
  short* wt      = (zz < 4) ? wtr : wti;
  int mBase = (zz & 3) * 16;
  {
    int dl = t >> 2, mg = t & 3;
    f32x4 v = *(const f32x4*)(w + ((long)(dc * 64 + dl) * 512 + e) * 64 + mBase + mg * 4);
    tile[dl][mg*4+0] = v[0]; tile[dl][mg*4+1] = v[1];
    tile[dl][mg*4+2] = v[2]; tile[dl][mg*4+3] = v[3];
  }
  __syncthreads();
  if (t < 128) {
    int mr = t >> 3, dg = t & 7;
    short8 o;
    #pragma unroll
    for (int j = 0; j < 8; ++j) o[j] = f2b(tile[dg * 8 + j][mr]);
    *(short8*)(wt + ((long)(mBase + mr) * 512 + e) * 512 + dc * 64 + dg * 8) = o;
  }
}

// ---------------- x[b][l][d] f32 -> xt[b][d][l] bf16 ----------------
__global__ __launch_bounds__(256) void transpose_x(const float* __restrict__ x,
                                                   short* __restrict__ xt) {
  __shared__ float tile[64][65];
  int dc = blockIdx.x, lc = blockIdx.y, b = blockIdx.z, t = threadIdx.x;
  const float* xb = x + (long)b * L_ * D_;
  #pragma unroll
  for (int i = 0; i < 4; ++i) {
    int idx = i * 256 + t; int ll = idx >> 4, dg = idx & 15;
    f32x4 v = *(const f32x4*)(xb + (long)(lc * 64 + ll) * D_ + dc * 64 + dg * 4);
    tile[ll][dg*4+0] = v[0]; tile[ll][dg*4+1] = v[1];
    tile[ll][dg*4+2] = v[2]; tile[ll][dg*4+3] = v[3];
  }
  __syncthreads();
  #pragma unroll
  for (int i = 0; i < 2; ++i) {
    int idx = i * 256 + t; int dl = idx >> 3, lg = idx & 7;
    short8 o;
    #pragma unroll
    for (int j = 0; j < 8; ++j) o[j] = f2b(tile[lg * 8 + j][dl]);
    *(short8*)(xt + ((long)b * D_ + dc * 64 + dl) * L_ + lc * 64 + lg * 8) = o;
  }
}

// ---------------- 64x64-tile bf16 MFMA GEMM (dbuf + counted vmcnt) ----------------
template<bool RELU, bool HASBIAS>
__global__ __launch_bounds__(256) void gemm64(
    const short* __restrict__ A, long ldA,
    const short* __restrict__ W, long ldW,
    const float* __restrict__ bias,
    short* __restrict__ outB, long csr, long csc, int K)
{
  __shared__ short lA[2][64 * 64];
  __shared__ short lW[2][64 * 64];
  const int t = threadIdx.x, lane = t & 63, wid = t >> 6;
  const int quad = lane >> 4, l15 = lane & 15;
  const int wm = (wid & 1) * 32, wn = (wid >> 1) * 32;
  const long row0 = (long)blockIdx.x * 64, col0 = (long)blockIdx.y * 64;
  const short* Ab = A + row0 * ldA;
  const short* Wb = W + col0 * ldW;

  int srcrow[2]; long srcoff[2];
  #pragma unroll
  for (int i = 0; i < 2; ++i) {
    int c = wid * 2 + i;
    int r = c * 8 + (lane >> 3);
    int g = (lane & 7) ^ (r & 7);
    srcrow[i] = r; srcoff[i] = g * 8;
  }

  f32x4 acc[2][2];
  #pragma unroll
  for (int i = 0; i < 2; ++i)
    #pragma unroll
    for (int j = 0; j < 2; ++j) acc[i][j] = zero4();

  const int nk = K >> 6;
  #pragma unroll
  for (int i = 0; i < 2; ++i) {
    int c = wid * 2 + i;
    GLDS16(Ab + (long)srcrow[i] * ldA + srcoff[i], lA[0] + c * 512);
    GLDS16(Wb + (long)srcrow[i] * ldW + srcoff[i], lW[0] + c * 512);
  }
  if (nk > 1) {
    #pragma unroll
    for (int i = 0; i < 2; ++i) {
      int c = wid * 2 + i;
      GLDS16(Ab + (long)srcrow[i] * ldA + 64 + srcoff[i], lA[1] + c * 512);
      GLDS16(Wb + (long)srcrow[i] * ldW + 64 + srcoff[i], lW[1] + c * 512);
    }
  }

  for (int it = 0; it < nk; ++it) {
    if (it + 1 < nk) asm volatile("s_waitcnt vmcnt(4)" ::: "memory");
    else             asm volatile("s_waitcnt vmcnt(0)" ::: "memory");
    __builtin_amdgcn_s_barrier();
    const int cur = it & 1;
    const short* bufA = lA[cur];
    const short* bufW = lW[cur];
    #pragma unroll
    for (int ks = 0; ks < 2; ++ks) {
      int gq = ks * 4 + quad;
      short8 a0 = *(const short8*)&bufA[SWZ(wm + l15, gq)];
      short8 a1 = *(const short8*)&bufA[SWZ(wm + 16 + l15, gq)];
      short8 b0 = *(const short8*)&bufW[SWZ(wn + l15, gq)];
      short8 b1 = *(const short8*)&bufW[SWZ(wn + 16 + l15, gq)];
      acc[0][0] = MFMA(a0, b0, acc[0][0]);
      acc[0][1] = MFMA(a0, b1, acc[0][1]);
      acc[1][0] = MFMA(a1, b0, acc[1][0]);
      acc[1][1] = MFMA(a1, b1, acc[1][1]);
    }
    asm volatile("s_waitcnt lgkmcnt(0)" ::: "memory");
    __builtin_amdgcn_s_barrier();
    const long kn = (long)(it + 2) * 64;
    if (kn < K) {
      #pragma unroll
      for (int i = 0; i < 2; ++i) {
        int c = wid * 2 + i;
        GLDS16(Ab + (long)srcrow[i] * ldA + kn + srcoff[i], lA[cur] + c * 512);
        GLDS16(Wb + (long)srcrow[i] * ldW + kn + srcoff[i], lW[cur] + c * 512);
      }
    }
  }

  #pragma unroll
  for (int ni = 0; ni < 2; ++ni) {
    long col = col0 + wn + ni * 16 + l15;
    float bvv = HASBIAS ? bias[col] : 0.f;
    #pragma unroll
    for (int mi = 0; mi < 2; ++mi) {
      #pragma unroll
      for (int r = 0; r < 4; ++r) {
        long row = row0 + wm + mi * 16 + quad * 4 + r;
        float v = acc[mi][ni][r];
        if (HASBIAS) v += bvv;
        if (RELU)    v = fmaxf(v, 0.f);
        outB[row * csr + col * csc] = f2b(v);
      }
    }
  }
}

// ---------------- 128x128-tile bf16 MFMA GEMM (dbuf + counted vmcnt) ----------------
template<bool RELU, bool HASBIAS, bool HASRES, bool RESB>
__global__ __launch_bounds__(256) void gemm128(
    const short* __restrict__ A, long ldA, long Az,
    const short* __restrict__ W, long ldW, long Wz,
    const float* __restrict__ bias,
    const void* __restrict__ res, long ldres, long resZ,
    short* __restrict__ outB, long ldC, long Cz, int K)
{
  __shared__ short lA[2][128 * 64];
  __shared__ short lW[2][128 * 64];
  const int t = threadIdx.x, lane = t & 63, wid = t >> 6;
  const int quad = lane >> 4, l15 = lane & 15;
  const int wm = (wid & 1) * 64, wn = (wid >> 1) * 64;
  const long row0 = (long)blockIdx.x * 128, col0 = (long)blockIdx.y * 128;
  const int z = blockIdx.z;
  const short* Ab = A + (long)z * Az + row0 * ldA;
  const short* Wb = W + (long)z * Wz + col0 * ldW;

  int srcrow[4]; long srcoff[4];
  #pragma unroll
  for (int i = 0; i < 4; ++i) {
    int c = wid * 4 + i;
    int r = c * 8 + (lane >> 3);
    int g = (lane & 7) ^ (r & 7);
    srcrow[i] = r; srcoff[i] = g * 8;
  }

  f32x4 acc[4][4];
  #pragma unroll
  for (int i = 0; i < 4; ++i)
    #pragma unroll
    for (int j = 0; j < 4; ++j) acc[i][j] = zero4();

  const int nk = K >> 6;
  #pragma unroll
  for (int i = 0; i < 4; ++i) {
    int c = wid * 4 + i;
    GLDS16(Ab + (long)srcrow[i] * ldA + srcoff[i], lA[0] + c * 512);
    GLDS16(Wb + (long)srcrow[i] * ldW + srcoff[i], lW[0] + c * 512);
  }
  if (nk > 1) {
    #pragma unroll
    for (int i = 0; i < 4; ++i) {
      int c = wid * 4 + i;
      GLDS16(Ab + (long)srcrow[i] * ldA + 64 + srcoff[i], lA[1] + c * 512);
      GLDS16(Wb + (long)srcrow[i] * ldW + 64 + srcoff[i], lW[1] + c * 512);
    }
  }

  for (int it = 0; it < nk; ++it) {
    if (it + 1 < nk) asm volatile("s_waitcnt vmcnt(8)" ::: "memory");
    else             asm volatile("s_waitcnt vmcnt(0)" ::: "memory");
    __builtin_amdgcn_s_barrier();
    const int cur = it & 1;
    const short* bufA = lA[cur];
    const short* bufW = lW[cur];
    #pragma unroll
    for (int ks = 0; ks < 2; ++ks) {
      int gq = ks * 4 + quad;
      short8 av[4], bv[4];
      #pragma unroll
      for (int mi = 0; mi < 4; ++mi) av[mi] = *(const short8*)&bufA[SWZ(wm + mi * 16 + l15, gq)];
      #pragma unroll
      for (int ni = 0; ni < 4; ++ni) bv[ni] = *(const short8*)&bufW[SWZ(wn + ni * 16 + l15, gq)];
      #pragma unroll
      for (int mi = 0; mi < 4; ++mi)
        #pragma unroll
        for (int ni = 0; ni < 4; ++ni)
          acc[mi][ni] = MFMA(av[mi], bv[ni], acc[mi][ni]);
    }
    asm volatile("s_waitcnt lgkmcnt(0)" ::: "memory");
    __builtin_amdgcn_s_barrier();
    const long kn = (long)(it + 2) * 64;
    if (kn < K) {
      #pragma unroll
      for (int i = 0; i < 4; ++i) {
        int c = wid * 4 + i;
        GLDS16(Ab + (long)srcrow[i] * ldA + kn + srcoff[i], lA[cur] + c * 512);
        GLDS16(Wb + (long)srcrow[i] * ldW + kn + srcoff[i], lW[cur] + c * 512);
      }
    }
  }

  #pragma unroll
  for (int ni = 0; ni < 4; ++ni) {
    long col = col0 + wn + ni * 16 + l15;
    float bvv = HASBIAS ? bias[col] : 0.f;
    #pragma unroll
    for (int mi = 0; mi < 4; ++mi) {
      #pragma unroll
      for (int r = 0; r < 4; ++r) {
        long row = row0 + wm + mi * 16 + quad * 4 + r;
        float v = acc[mi][ni][r];
        if (HASBIAS) v += bvv;
        if (RELU)    v = fmaxf(v, 0.f);
        if (HASRES) {
          long ro = (long)z * resZ + row * ldres + col;
          v += RESB ? b2f(((const short*)res)[ro]) : ((const float*)res)[ro];
        }
        outB[(long)z * Cz + row * ldC + col] = f2b(v);
      }
    }
  }
}

// ---------------- 256x256-tile bf16 MFMA GEMM, v2 ----------------
// 512 threads = 8 waves (2M x 4N); per-wave output 128x64; BK=64.
// One compute region per K-tile (2 barriers/K-tile). ds_reads are inline-asm
// (opaque to alias analysis => no compiler-inserted vmcnt(0) vs GLDS16).
// Per K-tile per wave: 24 unique ds_read_b128 (B 8, A0 8, A1 8);
// lgkmcnt(8) -> 32 MFMA (QM=0, B reg-cached); lgkmcnt(0) -> 32 MFMA (QM=1).
// Staging: 8 GLDS16 for tile i+1 at top of iter i; vmcnt(8) counted wait
// (vmcnt(0) only on last tile). Requires K%64==0, M,N%256==0, grid%8==0.
template<bool RELU, bool HASRES>
__global__ __launch_bounds__(512, 2) void gemm256(
    const short* __restrict__ A, long ldA,
    const short* __restrict__ W, long ldW,
    const short* __restrict__ res, long ldres,
    short* __restrict__ outB, long ldC, int K, int gn)
{
  __shared__ short sh[65536];           // 128 KiB: A bytes [0,64K), B [64K,128K)
  const int t = threadIdx.x;
  const int lane = t & 63, wid = t >> 6;
  const int quad = lane >> 4, l15 = lane & 15;
  const int wr = wid >> 2, wc = wid & 3;
  const int wch = wc >> 1, cbw = (wc & 1) * 64;

  // XCD-aware swizzle (grid % 8 == 0 guaranteed by caller)
  const int nwg = gridDim.x, cpx = nwg >> 3;
  const int wg = (blockIdx.x & 7) * cpx + (blockIdx.x >> 3);
  const int bx = wg / gn, by = wg - bx * gn;
  const long row0 = (long)bx * 256, col0 = (long)by * 256;
  const short* Ab = A + row0 * ldA;
  const short* Wb = W + col0 * ldW;

  // staging geometry: linear LDS dest (wave-uniform + lane*16B), source k-group
  // pre-swizzled so linear write + swizzled read are the same involution.
  const int srw = t >> 3;
  const int sg  = (t & 7) ^ (srw & 7);

#define STAGE(TP, KB) do {                                                   \
    const long ko_ = (long)(KB) + sg * 8;                                    \
    _Pragma("unroll")                                                        \
    for (int h_ = 0; h_ < 2; ++h_) {                                         \
      short* dA_ = sh + ((TP) * 2 + h_) * 8192;                              \
      short* dB_ = sh + 32768 + ((TP) * 2 + h_) * 8192;                      \
      _Pragma("unroll")                                                      \
      for (int j_ = 0; j_ < 2; ++j_) {                                       \
        const long gr_ = (long)(h_ * 128 + srw + j_ * 64);                   \
        GLDS16(Ab + gr_ * ldA + ko_, dA_ + (j_ * 512 + t) * 8);              \
        GLDS16(Wb + gr_ * ldW + ko_, dB_ + (j_ * 512 + t) * 8);              \
      }                                                                      \
    }                                                                        \
  } while (0)

  // per-thread read base offsets (bytes, AS3)
  const unsigned shb  = ldsaddr(sh);
  const unsigned swz0 = (unsigned)((quad ^ (l15 & 7)) << 4);
  const unsigned swz1 = swz0 ^ 64u;
  const unsigned aB = shb + wr * 16384u + (unsigned)(l15 * 128);
  const unsigned bB = shb + 65536u + wch * 16384u + (unsigned)((cbw + l15) * 128);

  f32x4 acc[8][4];
  #pragma unroll
  for (int i = 0; i < 8; ++i)
    #pragma unroll
    for (int j = 0; j < 4; ++j) acc[i][j] = zero4();

  const int NK = K >> 6;
  STAGE(0, 0);                 // prologue: tile 0 -> slot 0

  for (int i = 0; i < NK; ++i) {
    const unsigned tpo = (unsigned)(i & 1) * 32768u;
    if (i + 1 < NK) {
      STAGE((i + 1) & 1, (i + 1) << 6);          // 8 loads, tile i+1
      asm volatile("s_waitcnt vmcnt(8)" ::: "memory");   // tile i resident
    } else {
      asm volatile("s_waitcnt vmcnt(0)" ::: "memory");
    }
    __builtin_amdgcn_s_barrier();
    __builtin_amdgcn_sched_barrier(0);

    short8 bv[4][2], a0[4][2], a1[4][2];
    #pragma unroll
    for (int ni = 0; ni < 4; ++ni) {
      bv[ni][0] = dsr128(bB + tpo + ni * 2048u + swz0);
      bv[ni][1] = dsr128(bB + tpo + ni * 2048u + swz1);
    }
    #pragma unroll
    for (int u = 0; u < 4; ++u) {
      a0[u][0] = dsr128(aB + tpo + u * 2048u + swz0);
      a0[u][1] = dsr128(aB + tpo + u * 2048u + swz1);
    }
    #pragma unroll
    for (int u = 0; u < 4; ++u) {
      a1[u][0] = dsr128(aB + tpo + 8192u + u * 2048u + swz0);
      a1[u][1] = dsr128(aB + tpo + 8192u + u * 2048u + swz1);
    }
    asm volatile("s_waitcnt lgkmcnt(8)" ::: "memory");  // B + A0 complete
    __builtin_amdgcn_sched_barrier(0);
    __builtin_amdgcn_s_setprio(1);
    #pragma unroll
    for (int ks = 0; ks < 2; ++ks)
      #pragma unroll
      for (int u = 0; u < 4; ++u)
        #pragma unroll
        for (int ni = 0; ni < 4; ++ni)
          acc[u][ni] = MFMA(a0[u][ks], bv[ni][ks], acc[u][ni]);
    __builtin_amdgcn_s_setprio(0);
    asm volatile("s_waitcnt lgkmcnt(0)" ::: "memory");  // A1 complete
    __builtin_amdgcn_sched_barrier(0);
    __builtin_amdgcn_s_setprio(1);
    #pragma unroll
    for (int ks = 0; ks < 2; ++ks)
      #pragma unroll
      for (int u = 0; u < 4; ++u)
        #pragma unroll
        for (int ni = 0; ni < 4; ++ni)
          acc[4 + u][ni] = MFMA(a1[u][ks], bv[ni][ks], acc[4 + u][ni]);
    __builtin_amdgcn_s_setprio(0);
    __builtin_amdgcn_sched_barrier(0);
    __builtin_amdgcn_s_barrier();   // all waves done reading slot (i&1)
  }

  // ---- epilogue ----
  #pragma unroll
  for (int ni = 0; ni < 4; ++ni) {
    long col = col0 + wc * 64 + ni * 16 + l15;
    #pragma unroll
    for (int mi = 0; mi < 8; ++mi) {
      #pragma unroll
      for (int r = 0; r < 4; ++r) {
        long row = row0 + wr * 128 + mi * 16 + quad * 4 + r;
        float v = acc[mi][ni][r];
        if (RELU) v = fmaxf(v, 0.f);
        if (HASRES) v += b2f(res[row * ldres + col]);
        outB[row * ldC + col] = f2b(v);
      }
    }
  }
#undef STAGE
}

// ---------------- per-mode complex GEMM ----------------
__global__ __launch_bounds__(256) void mode_gemm(
    const short* __restrict__ qr, const short* __restrict__ qi,
    const short* __restrict__ wr, const short* __restrict__ wi,
    short* __restrict__ outm)
{
  __shared__ short lqr[16 * 64], lqi[16 * 64], lwr[64 * 64], lwi[64 * 64];
  const int m = blockIdx.x, en = blockIdx.y;
  const int t = threadIdx.x, lane = t & 63, wid = t >> 6;
  const int quad = lane >> 4, l15 = lane & 15;
  const short* qrb = qr + (long)m * (B_ * D_);
  const short* qib = qi + (long)m * (B_ * D_);
  const short* wrb = wr + (long)m * (D_ * D_) + (long)en * 64 * D_;
  const short* wib = wi + (long)m * (D_ * D_) + (long)en * 64 * D_;
  f32x4 accr = zero4(), acci = zero4();
  for (int k0 = 0; k0 < D_; k0 += 64) {
    __syncthreads();
    {
      int idx = t & 127; int r = idx >> 3, cg = idx & 7;
      const short* src = (t < 128 ? qrb : qib) + r * D_ + k0 + cg * 8;
      short* dst = (t < 128) ? lqr : lqi;
      *(short8*)&dst[SWZ(r, cg)] = *(const short8*)src;
    }
    #pragma unroll
    for (int i = 0; i < 4; ++i) {
      int idx = i * 256 + t;
      int which = idx >> 9, idx2 = idx & 511;
      int r = idx2 >> 3, cg = idx2 & 7;
      const short* src = (which ? wib : wrb) + r * D_ + k0 + cg * 8;
      short* dst = which ? lwi : lwr;
      *(short8*)&dst[SWZ(r, cg)] = *(const short8*)src;
    }
    __syncthreads();
    #pragma unroll
    for (int ks = 0; ks < 2; ++ks) {
      int gq = ks * 4 + quad;
      short8 ar = *(const short8*)&lqr[SWZ(l15, gq)];
      short8 ai = *(const short8*)&lqi[SWZ(l15, gq)];
      short8 br = *(const short8*)&lwr[SWZ(wid * 16 + l15, gq)];
      short8 bi = *(const short8*)&lwi[SWZ(wid * 16 + l15, gq)];
      short8 nai;
      #pragma unroll
      for (int j = 0; j < 8; ++j) nai[j] = (short)(ai[j] ^ (short)0x8000);
      accr = MFMA(ar, br, accr);
      accr = MFMA(nai, bi, accr);   // - qi*wi
      acci = MFMA(ar, bi, acci);
      acci = MFMA(ai, br, acci);
    }
  }
  #pragma unroll
  for (int r = 0; r < 4; ++r) {
    int bb = quad * 4 + r;
    long e = (long)en * 64 + wid * 16 + l15;
    long base = ((long)bb * D_ + e) * 128 + m;
    outm[base]      = f2b(accr[r]);
    outm[base + 64] = f2b(acci[r]);
  }
}

// ---------------- fused gates + seasonal combine ----------------
template<bool OUTF, bool WRITEB>
__global__ __launch_bounds__(512) void combine_kernel(
    const short* __restrict__ xin, const short* __restrict__ h,
    const float* __restrict__ w2, const float* __restrict__ b2,
    float* __restrict__ outf, short* __restrict__ outb)
{
  __shared__ float lG[64][4];
  int lc = blockIdx.x, b = blockIdx.y, t = threadIdx.x;
  int wid = t >> 6, lane = t & 63;
  int l0 = lc * 64;
  #pragma unroll
  for (int pi = 0; pi < 8; ++pi) {
    int pos = wid * 8 + pi;
    long row = (long)b * L_ + l0 + pos;
    short4v hh = *(const short4v*)(h + row * HID + lane * 4);
    float hv[4];
    #pragma unroll
    for (int j = 0; j < 4; ++j) hv[j] = b2f(hh[j]);
    float lg[3];
    #pragma unroll
    for (int e = 0; e < 3; ++e) {
      const float* wrow = w2 + e * HID + lane * 4;
      float p = hv[0] * wrow[0] + hv[1] * wrow[1] + hv[2] * wrow[2] + hv[3] * wrow[3];
      #pragma unroll
      for (int off = 32; off >= 1; off >>= 1) p += __shfl_xor(p, off);
      lg[e] = p + b2[e];
    }
    float mx = fmaxf(lg[0], fmaxf(lg[1], lg[2]));
    float e0 = __expf(lg[0] - mx), e1 = __expf(lg[1] - mx), e2 = __expf(lg[2] - mx);
    float inv = 1.f / (e0 + e1 + e2);
    float gv = (lane == 0) ? e0 * inv : (lane == 1) ? e1 * inv : e2 * inv;
    if (lane < 3) lG[pos][lane] = gv;
  }
  __syncthreads();

  int d = t;  // 512 threads = D
  const short* xb = xin + (long)b * L_ * D_ + d;
  float win[7];
  #pragma unroll
  for (int j = 0; j < 6; ++j) {
    int l = l0 - 3 + j;
    win[j] = (l >= 0 && l < L_) ? b2f(xb[(long)l * D_]) : 0.f;
  }
  for (int i = 0; i < 64; ++i) {
    int lcn = l0 + i;
    int lr = lcn + 3;
    win[6] = (lr < L_) ? b2f(xb[(long)lr * D_]) : 0.f;
    float s3 = win[2] + win[3] + win[4];
    float s5 = s3 + win[1] + win[5];
    float s7 = s5 + win[0] + win[6];
    float trend = lG[i][0] * s3 * (1.f / 3.f) + lG[i][1] * s5 * (1.f / 5.f)
                + lG[i][2] * s7 * (1.f / 7.f);
    float v = win[3] - trend;
    long o = ((long)b * L_ + lcn) * D_ + d;
    if (OUTF)   outf[o] = v;
    if (WRITEB) outb[o] = f2b(v);
    #pragma unroll
    for (int j = 0; j < 6; ++j) win[j] = win[j + 1];
  }
}

extern "C" void kernel_launch(void* const* d_in, const int* in_sizes, int n_in,
                              void* d_out, int out_size, void* d_ws, size_t ws_size,
                              hipStream_t stream) {
  const float* x       = (const float*)d_in[0];
  const float* w_real  = (const float*)d_in[1];
  const float* w_imag  = (const float*)d_in[2];
  const float* conv1_w = (const float*)d_in[3];
  const float* conv2_w = (const float*)d_in[4];
  const float* d1_w1   = (const float*)d_in[5];
  const float* d1_b1   = (const float*)d_in[6];
  const float* d1_w2   = (const float*)d_in[7];
  const float* d1_b2   = (const float*)d_in[8];
  const float* d2_w1   = (const float*)d_in[9];
  const float* d2_b1   = (const float*)d_in[10];
  const float* d2_w2   = (const float*)d_in[11];
  const float* d2_b2   = (const float*)d_in[12];
  float* OUT = (float*)d_out;

  const size_t REQ_BIG = 144703488, REQ_SMALL = 98566144;
  if (ws_size < REQ_SMALL) {
    zero_out<<<(out_size + 255) / 256, 256, 0, stream>>>(OUT, out_size);
    return;
  }
  const bool big = (ws_size >= REQ_BIG);

  char* ws = (char*)d_ws;
  short* C1WB  = (short*)(ws + 0);          //  2,097,152
  short* C2WB  = (short*)(ws + 2097152);    //  2,097,152
  short* D1W1B = (short*)(ws + 4194304);    //    262,144
  short* D2W1B = (short*)(ws + 4456448);    //    262,144
  short* TCS   = (short*)(ws + 4718592);    //    393,216
  short* BASIS = (short*)(ws + 5111808);    //    393,216 (pad -> 6,291,456)
  short* XT    = (short*)(ws + 6291456);    // 25,165,824 [dead after fwdDFT]
  short* Y1    = XT;                        // big:100.7MB / small:50.3MB [FFN phase]
  short* QRI   = (short*)(ws + 31457280);   //  2,097,152
  short* OUTM  = (short*)(ws + 33554432);   //  2,097,152
  short* WTR   = (short*)(ws + 35651584);   // 33,554,432 [dead after modes]
  short* X1B   = WTR;                       // 25,165,824 [alias]
  short* WTI   = (short*)(ws + 69206016);   // 33,554,432 [dead after modes]
  short* X2B   = (short*)(ws + (big ? 106954752 : 60817408));   // 25,165,824
  short* H     = (short*)(ws + (big ? 132120576 : 85983232));   // 12,582,912

  prep_all<<<3840, 256, 0, stream>>>(conv1_w, conv2_w, d1_w1, d2_w1,
                                     C1WB, C2WB, D1W1B, D2W1B, TCS, BASIS);
  transpose_w<<<dim3(8, 512, 8), 256, 0, stream>>>(w_real, w_imag, WTR, WTI);
  transpose_x<<<dim3(8, 24, 16), 256, 0, stream>>>(x, XT);

  gemm64<false, false><<<dim3(128, 2), 256, 0, stream>>>(
      XT, L_, TCS, L_, nullptr, QRI, 1, (long)B_ * D_, L_);

  mode_gemm<<<dim3(64, 8), 256, 0, stream>>>(QRI, QRI + 64 * B_ * D_, WTR, WTI, OUTM);

  gemm128<false, false, true, false><<<dim3(12, 4, 16), 256, 0, stream>>>(
      BASIS, 128, 0, OUTM, 128, (long)D_ * 128, nullptr,
      x, D_, (long)L_ * D_, X1B, D_, (long)L_ * D_, 128);

  gemm64<true, true><<<dim3(384, 4), 256, 0, stream>>>(
      X1B, D_, D1W1B, D_, d1_b1, H, HID, 1, D_);
  combine_kernel<false, true><<<dim3(24, 16), 512, 0, stream>>>(
      X1B, H, d1_w2, d1_b2, nullptr, X2B);

  // --- FFN via 256^2 GEMM v2 (big: single full-M pass; small: 2 chunks) ---
  {
    const int nchunk = big ? 1 : 2;
    const long rows = big ? 24576 : 12288;
    const int gm = (int)(rows / 256);
    for (int rc = 0; rc < nchunk; ++rc) {
      short* Ain = X2B + (long)rc * rows * D_;
      gemm256<true, false><<<dim3(gm * (DFF_ / 256)), 512, 0, stream>>>(
          Ain, D_, C1WB, D_, nullptr, 0, Y1, DFF_, D_, DFF_ / 256);
      gemm256<false, true><<<dim3(gm * (D_ / 256)), 512, 0, stream>>>(
          Y1, DFF_, C2WB, DFF_, Ain, D_, Ain, D_, DFF_, D_ / 256);
    }
  }

  gemm64<true, true><<<dim3(384, 4), 256, 0, stream>>>(
      X2B, D_, D2W1B, D_, d2_b1, H, HID, 1, D_);
  combine_kernel<true, false><<<dim3(24, 16), 512, 0, stream>>>(
      X2B, H, d2_w2, d2_b2, OUT, nullptr);
}

// Round 4
// 567.176 us; speedup vs baseline: 1.1126x; 1.0278x over previous
//
#include <hip/hip_runtime.h>

#define B_   16
#define L_   1536
#define D_   512
#define DFF_ 2048
#define NM   64
#define HID  256

typedef short short8  __attribute__((ext_vector_type(8)));
typedef short short4v __attribute__((ext_vector_type(4)));
typedef float f32x4   __attribute__((ext_vector_type(4)));

__device__ __forceinline__ float b2f(short s) {
  unsigned int u = ((unsigned int)(unsigned short)s) << 16;
  float f; __builtin_memcpy(&f, &u, 4); return f;
}
__device__ __forceinline__ short f2b(float f) {
  unsigned int u; __builtin_memcpy(&u, &f, 4);
  u += 0x7fffu + ((u >> 16) & 1u);
  return (short)(u >> 16);
}
__device__ __forceinline__ f32x4 zero4() {
  f32x4 v; v[0]=0.f; v[1]=0.f; v[2]=0.f; v[3]=0.f; return v;
}

#define MFMA(a,b,c) __builtin_amdgcn_mfma_f32_16x16x32_bf16((a),(b),(c),0,0,0)
// XOR-swizzled LDS offset (shorts) for 64-short rows: row*64 + (grp^(row&7))*8
#define SWZ(row, grp) (((row) << 6) + ((((grp) ^ ((row) & 7))) << 3))
// async 16B/lane global->LDS (m97: width 16 => global_load_lds_dwordx4)
#define GLDS16(gp, lp) __builtin_amdgcn_global_load_lds( \
    (const __attribute__((address_space(1))) void*)(gp), \
    (__attribute__((address_space(3))) void*)(lp), 16, 0, 0)
#define MEMFENCE asm volatile("" ::: "memory")
#define SB0 __builtin_amdgcn_sched_barrier(0)
#define LGKM4 asm volatile("s_waitcnt lgkmcnt(4)" ::: "memory")
#define LGKM0 asm volatile("s_waitcnt lgkmcnt(0)" ::: "memory")

// LDS byte address (AS3 offset) of a __shared__ pointer
__device__ __forceinline__ unsigned ldsaddr(const void* p) {
  return (unsigned)(unsigned long long)(const __attribute__((address_space(3))) void*)p;
}
// inline-asm ds_read_b128: opaque to alias analysis -> no compiler-inserted
// vmcnt(0) ordering vs global_load_lds; we count waits manually.
__device__ __forceinline__ short8 dsr128(unsigned a) {
  short8 r;
  asm volatile("ds_read_b128 %0, %1" : "=v"(r) : "v"(a));
  return r;
}

// ---------------- guard: zero output (ws too small diagnostic) ----------------
__global__ __launch_bounds__(256) void zero_out(float* __restrict__ o, int n) {
  int i = blockIdx.x * 256 + threadIdx.x;
  if (i < n) o[i] = 0.f;
}

// ---------------- fused prep: 4x f32->bf16 convert + DFT tables ----------------
__global__ __launch_bounds__(256) void prep_all(
    const float* __restrict__ conv1_w, const float* __restrict__ conv2_w,
    const float* __restrict__ d1_w1,  const float* __restrict__ d2_w1,
    short* __restrict__ c1, short* __restrict__ c2,
    short* __restrict__ dw1, short* __restrict__ dw2,
    short* __restrict__ tcs, short* __restrict__ basis)
{
  int blk = blockIdx.x;
  if (blk < 2304) {   // converts: pick source/dest
    const float* s; short* d; int i;
    if (blk < 1024)      { s = conv1_w; d = c1;  i = blk * 256 + threadIdx.x; }
    else if (blk < 2048) { s = conv2_w; d = c2;  i = (blk - 1024) * 256 + threadIdx.x; }
    else if (blk < 2176) { s = d1_w1;   d = dw1; i = (blk - 2048) * 256 + threadIdx.x; }
    else                 { s = d2_w1;   d = dw2; i = (blk - 2176) * 256 + threadIdx.x; }
    f32x4 v = ((const f32x4*)s)[i];
    short4v o;
    #pragma unroll
    for (int j = 0; j < 4; ++j) o[j] = f2b(v[j]);
    ((short4v*)d)[i] = o;
    return;
  }
  if (blk < 3072) {   // tcs[m][l], m<64: cos; m>=64: -sin
    int i = (blk - 2304) * 256 + threadIdx.x;
    int m = i / L_, l = i - m * L_;
    int mm = (m < 64) ? m : (m - 64);
    int r = (mm * l) % L_;
    float th = (float)r * (6.283185307179586f / (float)L_);
    float s, c; __sincosf(th, &s, &c);
    tcs[i] = f2b((m < 64) ? c : -s);
    return;
  }
  {   // basis[l][k]
    int i = (blk - 3072) * 256 + threadIdx.x;
    int l = i >> 7, k = i & 127;
    int m = (k < 64) ? k : (k - 64);
    int r = (m * l) % L_;
    float th = (float)r * (6.283185307179586f / (float)L_);
    float s, c; __sincosf(th, &s, &c);
    float v = (k < 64) ? ((m == 0) ? 1.f : 2.f) * (1.f / (float)L_) * c
                       : (-2.f / (float)L_) * s;
    basis[i] = f2b(v);
  }
}

// ---------------- w[d][e][m] f32 -> wt[m][e][d] bf16; z<4 real, z>=4 imag ----------------
__global__ __launch_bounds__(256) void transpose_w(
    const float* __restrict__ wre, const float* __restrict__ wim,
    short* __restrict__ wtr, short* __restrict__ wti)
{
  __shared__ float tile[64][17];
  int dc = blockIdx.x, e = blockIdx.y, t = threadIdx.x;
  int zz = blockIdx.z;
  const float* w = (zz < 4) ? wre : wim;
  short* wt      = (zz < 4) ? wtr : wti;
  int mBase = (zz & 3) * 16;
  {
    int dl = t >> 2, mg = t & 3;
    f32x4 v = *(const f32x4*)(w + ((long)(dc * 64 + dl) * 512 + e) * 64 + mBase + mg * 4);
    tile[dl][mg*4+0] = v[0]; tile[dl][mg*4+1] = v[1];
    tile[dl][mg*4+2] = v[2]; tile[dl][mg*4+3] = v[3];
  }
  __syncthreads();
  if (t < 128) {
    int mr = t >> 3, dg = t & 7;
    short8 o;
    #pragma unroll
    for (int j = 0; j < 8; ++j) o[j] = f2b(tile[dg * 8 + j][mr]);
    *(short8*)(wt + ((long)(mBase + mr) * 512 + e) * 512 + dc * 64 + dg * 8) = o;
  }
}

// ---------------- x[b][l][d] f32 -> xt[b][d][l] bf16 ----------------
__global__ __launch_bounds__(256) void transpose_x(const float* __restrict__ x,
                                                   short* __restrict__ xt) {
  __shared__ float tile[64][65];
  int dc = blockIdx.x, lc = blockIdx.y, b = blockIdx.z, t = threadIdx.x;
  const float* xb = x + (long)b * L_ * D_;
  #pragma unroll
  for (int i = 0; i < 4; ++i) {
    int idx = i * 256 + t; int ll = idx >> 4, dg = idx & 15;
    f32x4 v = *(const f32x4*)(xb + (long)(lc * 64 + ll) * D_ + dc * 64 + dg * 4);
    tile[ll][dg*4+0] = v[0]; tile[ll][dg*4+1] = v[1];
    tile[ll][dg*4+2] = v[2]; tile[ll][dg*4+3] = v[3];
  }
  __syncthreads();
  #pragma unroll
  for (int i = 0; i < 2; ++i) {
    int idx = i * 256 + t; int dl = idx >> 3, lg = idx & 7;
    short8 o;
    #pragma unroll
    for (int j = 0; j < 8; ++j) o[j] = f2b(tile[lg * 8 + j][dl]);
    *(short8*)(xt + ((long)b * D_ + dc * 64 + dl) * L_ + lc * 64 + lg * 8) = o;
  }
}

// ---------------- 64x64-tile bf16 MFMA GEMM (dbuf + counted vmcnt) ----------------
template<bool RELU, bool HASBIAS>
__global__ __launch_bounds__(256) void gemm64(
    const short* __restrict__ A, long ldA,
    const short* __restrict__ W, long ldW,
    const float* __restrict__ bias,
    short* __restrict__ outB, long csr, long csc, int K)
{
  __shared__ short lA[2][64 * 64];
  __shared__ short lW[2][64 * 64];
  const int t = threadIdx.x, lane = t & 63, wid = t >> 6;
  const int quad = lane >> 4, l15 = lane & 15;
  const int wm = (wid & 1) * 32, wn = (wid >> 1) * 32;
  const long row0 = (long)blockIdx.x * 64, col0 = (long)blockIdx.y * 64;
  const short* Ab = A + row0 * ldA;
  const short* Wb = W + col0 * ldW;

  int srcrow[2]; long srcoff[2];
  #pragma unroll
  for (int i = 0; i < 2; ++i) {
    int c = wid * 2 + i;
    int r = c * 8 + (lane >> 3);
    int g = (lane & 7) ^ (r & 7);
    srcrow[i] = r; srcoff[i] = g * 8;
  }

  f32x4 acc[2][2];
  #pragma unroll
  for (int i = 0; i < 2; ++i)
    #pragma unroll
    for (int j = 0; j < 2; ++j) acc[i][j] = zero4();

  const int nk = K >> 6;
  #pragma unroll
  for (int i = 0; i < 2; ++i) {
    int c = wid * 2 + i;
    GLDS16(Ab + (long)srcrow[i] * ldA + srcoff[i], lA[0] + c * 512);
    GLDS16(Wb + (long)srcrow[i] * ldW + srcoff[i], lW[0] + c * 512);
  }
  if (nk > 1) {
    #pragma unroll
    for (int i = 0; i < 2; ++i) {
      int c = wid * 2 + i;
      GLDS16(Ab + (long)srcrow[i] * ldA + 64 + srcoff[i], lA[1] + c * 512);
      GLDS16(Wb + (long)srcrow[i] * ldW + 64 + srcoff[i], lW[1] + c * 512);
    }
  }

  for (int it = 0; it < nk; ++it) {
    if (it + 1 < nk) asm volatile("s_waitcnt vmcnt(4)" ::: "memory");
    else             asm volatile("s_waitcnt vmcnt(0)" ::: "memory");
    __builtin_amdgcn_s_barrier();
    const int cur = it & 1;
    const short* bufA = lA[cur];
    const short* bufW = lW[cur];
    #pragma unroll
    for (int ks = 0; ks < 2; ++ks) {
      int gq = ks * 4 + quad;
      short8 a0 = *(const short8*)&bufA[SWZ(wm + l15, gq)];
      short8 a1 = *(const short8*)&bufA[SWZ(wm + 16 + l15, gq)];
      short8 b0 = *(const short8*)&bufW[SWZ(wn + l15, gq)];
      short8 b1 = *(const short8*)&bufW[SWZ(wn + 16 + l15, gq)];
      acc[0][0] = MFMA(a0, b0, acc[0][0]);
      acc[0][1] = MFMA(a0, b1, acc[0][1]);
      acc[1][0] = MFMA(a1, b0, acc[1][0]);
      acc[1][1] = MFMA(a1, b1, acc[1][1]);
    }
    asm volatile("s_waitcnt lgkmcnt(0)" ::: "memory");
    __builtin_amdgcn_s_barrier();
    const long kn = (long)(it + 2) * 64;
    if (kn < K) {
      #pragma unroll
      for (int i = 0; i < 2; ++i) {
        int c = wid * 2 + i;
        GLDS16(Ab + (long)srcrow[i] * ldA + kn + srcoff[i], lA[cur] + c * 512);
        GLDS16(Wb + (long)srcrow[i] * ldW + kn + srcoff[i], lW[cur] + c * 512);
      }
    }
  }

  #pragma unroll
  for (int ni = 0; ni < 2; ++ni) {
    long col = col0 + wn + ni * 16 + l15;
    float bvv = HASBIAS ? bias[col] : 0.f;
    #pragma unroll
    for (int mi = 0; mi < 2; ++mi) {
      #pragma unroll
      for (int r = 0; r < 4; ++r) {
        long row = row0 + wm + mi * 16 + quad * 4 + r;
        float v = acc[mi][ni][r];
        if (HASBIAS) v += bvv;
        if (RELU)    v = fmaxf(v, 0.f);
        outB[row * csr + col * csc] = f2b(v);
      }
    }
  }
}

// ---------------- 128x128-tile bf16 MFMA GEMM (dbuf + counted vmcnt) ----------------
template<bool RELU, bool HASBIAS, bool HASRES, bool RESB>
__global__ __launch_bounds__(256) void gemm128(
    const short* __restrict__ A, long ldA, long Az,
    const short* __restrict__ W, long ldW, long Wz,
    const float* __restrict__ bias,
    const void* __restrict__ res, long ldres, long resZ,
    short* __restrict__ outB, long ldC, long Cz, int K)
{
  __shared__ short lA[2][128 * 64];
  __shared__ short lW[2][128 * 64];
  const int t = threadIdx.x, lane = t & 63, wid = t >> 6;
  const int quad = lane >> 4, l15 = lane & 15;
  const int wm = (wid & 1) * 64, wn = (wid >> 1) * 64;
  const long row0 = (long)blockIdx.x * 128, col0 = (long)blockIdx.y * 128;
  const int z = blockIdx.z;
  const short* Ab = A + (long)z * Az + row0 * ldA;
  const short* Wb = W + (long)z * Wz + col0 * ldW;

  int srcrow[4]; long srcoff[4];
  #pragma unroll
  for (int i = 0; i < 4; ++i) {
    int c = wid * 4 + i;
    int r = c * 8 + (lane >> 3);
    int g = (lane & 7) ^ (r & 7);
    srcrow[i] = r; srcoff[i] = g * 8;
  }

  f32x4 acc[4][4];
  #pragma unroll
  for (int i = 0; i < 4; ++i)
    #pragma unroll
    for (int j = 0; j < 4; ++j) acc[i][j] = zero4();

  const int nk = K >> 6;
  #pragma unroll
  for (int i = 0; i < 4; ++i) {
    int c = wid * 4 + i;
    GLDS16(Ab + (long)srcrow[i] * ldA + srcoff[i], lA[0] + c * 512);
    GLDS16(Wb + (long)srcrow[i] * ldW + srcoff[i], lW[0] + c * 512);
  }
  if (nk > 1) {
    #pragma unroll
    for (int i = 0; i < 4; ++i) {
      int c = wid * 4 + i;
      GLDS16(Ab + (long)srcrow[i] * ldA + 64 + srcoff[i], lA[1] + c * 512);
      GLDS16(Wb + (long)srcrow[i] * ldW + 64 + srcoff[i], lW[1] + c * 512);
    }
  }

  for (int it = 0; it < nk; ++it) {
    if (it + 1 < nk) asm volatile("s_waitcnt vmcnt(8)" ::: "memory");
    else             asm volatile("s_waitcnt vmcnt(0)" ::: "memory");
    __builtin_amdgcn_s_barrier();
    const int cur = it & 1;
    const short* bufA = lA[cur];
    const short* bufW = lW[cur];
    #pragma unroll
    for (int ks = 0; ks < 2; ++ks) {
      int gq = ks * 4 + quad;
      short8 av[4], bv[4];
      #pragma unroll
      for (int mi = 0; mi < 4; ++mi) av[mi] = *(const short8*)&bufA[SWZ(wm + mi * 16 + l15, gq)];
      #pragma unroll
      for (int ni = 0; ni < 4; ++ni) bv[ni] = *(const short8*)&bufW[SWZ(wn + ni * 16 + l15, gq)];
      #pragma unroll
      for (int mi = 0; mi < 4; ++mi)
        #pragma unroll
        for (int ni = 0; ni < 4; ++ni)
          acc[mi][ni] = MFMA(av[mi], bv[ni], acc[mi][ni]);
    }
    asm volatile("s_waitcnt lgkmcnt(0)" ::: "memory");
    __builtin_amdgcn_s_barrier();
    const long kn = (long)(it + 2) * 64;
    if (kn < K) {
      #pragma unroll
      for (int i = 0; i < 4; ++i) {
        int c = wid * 4 + i;
        GLDS16(Ab + (long)srcrow[i] * ldA + kn + srcoff[i], lA[cur] + c * 512);
        GLDS16(Wb + (long)srcrow[i] * ldW + kn + srcoff[i], lW[cur] + c * 512);
      }
    }
  }

  #pragma unroll
  for (int ni = 0; ni < 4; ++ni) {
    long col = col0 + wn + ni * 16 + l15;
    float bvv = HASBIAS ? bias[col] : 0.f;
    #pragma unroll
    for (int mi = 0; mi < 4; ++mi) {
      #pragma unroll
      for (int r = 0; r < 4; ++r) {
        long row = row0 + wm + mi * 16 + quad * 4 + r;
        float v = acc[mi][ni][r];
        if (HASBIAS) v += bvv;
        if (RELU)    v = fmaxf(v, 0.f);
        if (HASRES) {
          long ro = (long)z * resZ + row * ldres + col;
          v += RESB ? b2f(((const short*)res)[ro]) : ((const float*)res)[ro];
        }
        outB[(long)z * Cz + row * ldC + col] = f2b(v);
      }
    }
  }
}

// ---------------- BMx256-tile bf16 MFMA GEMM, v3: intra-tile lgkm pipeline ----------------
// 512 threads = 8 waves (2M x 4N); per-wave output (BM/2)x64; BK=64.
// Per K-tile per wave: B fully reg-cached (8 ds_read_b128), A in MF/2 pairs of
// 4 reads each, pipelined: issue pair p+1's reads, wait lgkmcnt(4) (pair p
// ready, p+1 in flight), 16 MFMA. DS completes in-order per wave => counted
// lgkm is exact. sched_barrier(0) after every wait (rule #18). 2 barriers and
// one counted vmcnt per K-tile; vmcnt(0) only at the last tile.
// BM=256: FFN1 (grid=exact multiples of 256 CUs). BM=192: FFN2 (grid 256 = 1/CU).
template<int BM, bool RELU, bool HASRES>
__global__ __launch_bounds__(512, 2) void gemmT(
    const short* __restrict__ A, long ldA,
    const short* __restrict__ W, long ldW,
    const short* __restrict__ res, long ldres,
    short* __restrict__ outB, long ldC, int K, int gn)
{
  constexpr int MF   = BM / 32;    // M-frags per wave (8 or 6)
  constexpr int ALD  = BM / 64;    // A stage loads per thread (4 or 3)
  __shared__ short sh[BM * 128 + 32768];   // A: 2 slots of BM*64 shorts; B: 2 of 16384
  const int t = threadIdx.x;
  const int lane = t & 63, wid = t >> 6;
  const int quad = lane >> 4, l15 = lane & 15;
  const int wr = wid >> 2, wc = wid & 3;

  // XCD-aware swizzle (grid % 8 == 0 guaranteed by caller)
  const int nwg = gridDim.x, cpx = nwg >> 3;
  const int wg = (blockIdx.x & 7) * cpx + (blockIdx.x >> 3);
  const int bx = wg / gn, by = wg - bx * gn;
  const long row0 = (long)bx * BM, col0 = (long)by * 256;
  const short* Ab = A + row0 * ldA;
  const short* Wb = W + col0 * ldW;

  // staging: linear LDS dest, source k-group pre-swizzled (involution with read)
  const int srw = t >> 3;
  const int sg  = (t & 7) ^ (srw & 7);

#define STAGE(TP, KB) do {                                                   \
    const long ko_ = (long)(KB) + sg * 8;                                    \
    short* dA_ = sh + (TP) * (BM * 64);                                      \
    short* dB_ = sh + BM * 128 + (TP) * 16384;                               \
    _Pragma("unroll")                                                        \
    for (int ld = 0; ld < ALD; ++ld)                                         \
      GLDS16(Ab + (long)(ld * 64 + srw) * ldA + ko_, dA_ + (ld * 512 + t) * 8); \
    _Pragma("unroll")                                                        \
    for (int ld = 0; ld < 4; ++ld)                                           \
      GLDS16(Wb + (long)(ld * 64 + srw) * ldW + ko_, dB_ + (ld * 512 + t) * 8); \
  } while (0)
  // counted vmcnt: one stage in flight = ALD+4 loads
#define WAITV() do {                                                         \
    if constexpr (BM == 256) asm volatile("s_waitcnt vmcnt(8)" ::: "memory");\
    else                     asm volatile("s_waitcnt vmcnt(7)" ::: "memory");\
  } while (0)

  // read bases (bytes, AS3)
  const unsigned shb  = ldsaddr(sh);
  const unsigned swz0 = (unsigned)((quad ^ (l15 & 7)) << 4);
  const unsigned swz1 = swz0 ^ 64u;
  const unsigned aBs = shb + (unsigned)(wr * (BM / 2) * 128) + (unsigned)(l15 * 128);
  const unsigned bBs = shb + (unsigned)(BM * 256) + (unsigned)((wc * 64 + l15) * 128);

#define RDP(BUF, AO, P) do {                                                 \
    BUF[0][0] = dsr128(aBs + (AO) + ((P) * 2 + 0) * 2048u + swz0);           \
    BUF[0][1] = dsr128(aBs + (AO) + ((P) * 2 + 0) * 2048u + swz1);           \
    BUF[1][0] = dsr128(aBs + (AO) + ((P) * 2 + 1) * 2048u + swz0);           \
    BUF[1][1] = dsr128(aBs + (AO) + ((P) * 2 + 1) * 2048u + swz1);           \
  } while (0)
#define MMAP(P, BUF) do {                                                    \
    __builtin_amdgcn_s_setprio(1);                                           \
    _Pragma("unroll")                                                        \
    for (int ks = 0; ks < 2; ++ks)                                           \
      _Pragma("unroll")                                                      \
      for (int u = 0; u < 2; ++u)                                            \
        _Pragma("unroll")                                                    \
        for (int ni = 0; ni < 4; ++ni)                                       \
          acc[(P) * 2 + u][ni] = MFMA(BUF[u][ks], bv[ni][ks], acc[(P)*2+u][ni]); \
    __builtin_amdgcn_s_setprio(0);                                           \
  } while (0)

  f32x4 acc[MF][4];
  #pragma unroll
  for (int i = 0; i < MF; ++i)
    #pragma unroll
    for (int j = 0; j < 4; ++j) acc[i][j] = zero4();

  const int NK = K >> 6;
  STAGE(0, 0);                 // prologue: tile 0 -> slot 0

  for (int i = 0; i < NK; ++i) {
    const unsigned ao = (unsigned)(i & 1) * (unsigned)(BM * 128);
    const unsigned bo = (unsigned)(i & 1) * 32768u;
    if (i + 1 < NK) {
      STAGE((i + 1) & 1, (i + 1) << 6);
      WAITV();                 // tile i resident (tile i+1 stays in flight)
    } else {
      asm volatile("s_waitcnt vmcnt(0)" ::: "memory");
    }
    __builtin_amdgcn_s_barrier();
    SB0;

    short8 bv[4][2], Aa[2][2], Abf[2][2], Ac[2][2];
    #pragma unroll
    for (int ni = 0; ni < 4; ++ni) {
      bv[ni][0] = dsr128(bBs + bo + ni * 2048u + swz0);
      bv[ni][1] = dsr128(bBs + bo + ni * 2048u + swz1);
    }
    RDP(Aa, ao, 0);
    RDP(Abf, ao, 1);
    LGKM4; SB0;                // B + pair0 ready; pair1 in flight
    RDP(Ac, ao, 2);
    MMAP(0, Aa);
    LGKM4; SB0;                // pair1 ready; pair2 in flight
    if constexpr (MF == 8) {
      RDP(Aa, ao, 3);          // reuse Aa (pair0 consumed)
      MMAP(1, Abf);
      LGKM4; SB0;              // pair2 ready; pair3 in flight
      MMAP(2, Ac);
      LGKM0; SB0;              // pair3 ready
      MMAP(3, Aa);
    } else {
      MMAP(1, Abf);
      LGKM0; SB0;              // pair2 ready
      MMAP(2, Ac);
    }
    __builtin_amdgcn_s_barrier();   // all waves done reading slot (i&1)
  }

  // ---- epilogue ----
  #pragma unroll
  for (int ni = 0; ni < 4; ++ni) {
    long col = col0 + wc * 64 + ni * 16 + l15;
    #pragma unroll
    for (int mi = 0; mi < MF; ++mi) {
      #pragma unroll
      for (int r = 0; r < 4; ++r) {
        long row = row0 + wr * (BM / 2) + mi * 16 + quad * 4 + r;
        float v = acc[mi][ni][r];
        if (RELU) v = fmaxf(v, 0.f);
        if (HASRES) v += b2f(res[row * ldres + col]);
        outB[row * ldC + col] = f2b(v);
      }
    }
  }
#undef STAGE
#undef WAITV
#undef RDP
#undef MMAP
}

// ---------------- per-mode complex GEMM ----------------
__global__ __launch_bounds__(256) void mode_gemm(
    const short* __restrict__ qr, const short* __restrict__ qi,
    const short* __restrict__ wr, const short* __restrict__ wi,
    short* __restrict__ outm)
{
  __shared__ short lqr[16 * 64], lqi[16 * 64], lwr[64 * 64], lwi[64 * 64];
  const int m = blockIdx.x, en = blockIdx.y;
  const int t = threadIdx.x, lane = t & 63, wid = t >> 6;
  const int quad = lane >> 4, l15 = lane & 15;
  const short* qrb = qr + (long)m * (B_ * D_);
  const short* qib = qi + (long)m * (B_ * D_);
  const short* wrb = wr + (long)m * (D_ * D_) + (long)en * 64 * D_;
  const short* wib = wi + (long)m * (D_ * D_) + (long)en * 64 * D_;
  f32x4 accr = zero4(), acci = zero4();
  for (int k0 = 0; k0 < D_; k0 += 64) {
    __syncthreads();
    {
      int idx = t & 127; int r = idx >> 3, cg = idx & 7;
      const short* src = (t < 128 ? qrb : qib) + r * D_ + k0 + cg * 8;
      short* dst = (t < 128) ? lqr : lqi;
      *(short8*)&dst[SWZ(r, cg)] = *(const short8*)src;
    }
    #pragma unroll
    for (int i = 0; i < 4; ++i) {
      int idx = i * 256 + t;
      int which = idx >> 9, idx2 = idx & 511;
      int r = idx2 >> 3, cg = idx2 & 7;
      const short* src = (which ? wib : wrb) + r * D_ + k0 + cg * 8;
      short* dst = which ? lwi : lwr;
      *(short8*)&dst[SWZ(r, cg)] = *(const short8*)src;
    }
    __syncthreads();
    #pragma unroll
    for (int ks = 0; ks < 2; ++ks) {
      int gq = ks * 4 + quad;
      short8 ar = *(const short8*)&lqr[SWZ(l15, gq)];
      short8 ai = *(const short8*)&lqi[SWZ(l15, gq)];
      short8 br = *(const short8*)&lwr[SWZ(wid * 16 + l15, gq)];
      short8 bi = *(const short8*)&lwi[SWZ(wid * 16 + l15, gq)];
      short8 nai;
      #pragma unroll
      for (int j = 0; j < 8; ++j) nai[j] = (short)(ai[j] ^ (short)0x8000);
      accr = MFMA(ar, br, accr);
      accr = MFMA(nai, bi, accr);   // - qi*wi
      acci = MFMA(ar, bi, acci);
      acci = MFMA(ai, br, acci);
    }
  }
  #pragma unroll
  for (int r = 0; r < 4; ++r) {
    int bb = quad * 4 + r;
    long e = (long)en * 64 + wid * 16 + l15;
    long base = ((long)bb * D_ + e) * 128 + m;
    outm[base]      = f2b(accr[r]);
    outm[base + 64] = f2b(acci[r]);
  }
}

// ---------------- fused gates + seasonal combine ----------------
template<bool OUTF, bool WRITEB>
__global__ __launch_bounds__(512) void combine_kernel(
    const short* __restrict__ xin, const short* __restrict__ h,
    const float* __restrict__ w2, const float* __restrict__ b2,
    float* __restrict__ outf, short* __restrict__ outb)
{
  __shared__ float lG[64][4];
  int lc = blockIdx.x, b = blockIdx.y, t = threadIdx.x;
  int wid = t >> 6, lane = t & 63;
  int l0 = lc * 64;
  #pragma unroll
  for (int pi = 0; pi < 8; ++pi) {
    int pos = wid * 8 + pi;
    long row = (long)b * L_ + l0 + pos;
    short4v hh = *(const short4v*)(h + row * HID + lane * 4);
    float hv[4];
    #pragma unroll
    for (int j = 0; j < 4; ++j) hv[j] = b2f(hh[j]);
    float lg[3];
    #pragma unroll
    for (int e = 0; e < 3; ++e) {
      const float* wrow = w2 + e * HID + lane * 4;
      float p = hv[0] * wrow[0] + hv[1] * wrow[1] + hv[2] * wrow[2] + hv[3] * wrow[3];
      #pragma unroll
      for (int off = 32; off >= 1; off >>= 1) p += __shfl_xor(p, off);
      lg[e] = p + b2[e];
    }
    float mx = fmaxf(lg[0], fmaxf(lg[1], lg[2]));
    float e0 = __expf(lg[0] - mx), e1 = __expf(lg[1] - mx), e2 = __expf(lg[2] - mx);
    float inv = 1.f / (e0 + e1 + e2);
    float gv = (lane == 0) ? e0 * inv : (lane == 1) ? e1 * inv : e2 * inv;
    if (lane < 3) lG[pos][lane] = gv;
  }
  __syncthreads();

  int d = t;  // 512 threads = D
  const short* xb = xin + (long)b * L_ * D_ + d;
  float win[7];
  #pragma unroll
  for (int j = 0; j < 6; ++j) {
    int l = l0 - 3 + j;
    win[j] = (l >= 0 && l < L_) ? b2f(xb[(long)l * D_]) : 0.f;
  }
  for (int i = 0; i < 64; ++i) {
    int lcn = l0 + i;
    int lr = lcn + 3;
    win[6] = (lr < L_) ? b2f(xb[(long)lr * D_]) : 0.f;
    float s3 = win[2] + win[3] + win[4];
    float s5 = s3 + win[1] + win[5];
    float s7 = s5 + win[0] + win[6];
    float trend = lG[i][0] * s3 * (1.f / 3.f) + lG[i][1] * s5 * (1.f / 5.f)
                + lG[i][2] * s7 * (1.f / 7.f);
    float v = win[3] - trend;
    long o = ((long)b * L_ + lcn) * D_ + d;
    if (OUTF)   outf[o] = v;
    if (WRITEB) outb[o] = f2b(v);
    #pragma unroll
    for (int j = 0; j < 6; ++j) win[j] = win[j + 1];
  }
}

extern "C" void kernel_launch(void* const* d_in, const int* in_sizes, int n_in,
                              void* d_out, int out_size, void* d_ws, size_t ws_size,
                              hipStream_t stream) {
  const float* x       = (const float*)d_in[0];
  const float* w_real  = (const float*)d_in[1];
  const float* w_imag  = (const float*)d_in[2];
  const float* conv1_w = (const float*)d_in[3];
  const float* conv2_w = (const float*)d_in[4];
  const float* d1_w1   = (const float*)d_in[5];
  const float* d1_b1   = (const float*)d_in[6];
  const float* d1_w2   = (const float*)d_in[7];
  const float* d1_b2   = (const float*)d_in[8];
  const float* d2_w1   = (const float*)d_in[9];
  const float* d2_b1   = (const float*)d_in[10];
  const float* d2_w2   = (const float*)d_in[11];
  const float* d2_b2   = (const float*)d_in[12];
  float* OUT = (float*)d_out;

  const size_t REQ_BIG = 144703488, REQ_SMALL = 98566144;
  if (ws_size < REQ_SMALL) {
    zero_out<<<(out_size + 255) / 256, 256, 0, stream>>>(OUT, out_size);
    return;
  }
  const bool big = (ws_size >= REQ_BIG);

  char* ws = (char*)d_ws;
  short* C1WB  = (short*)(ws + 0);          //  2,097,152
  short* C2WB  = (short*)(ws + 2097152);    //  2,097,152
  short* D1W1B = (short*)(ws + 4194304);    //    262,144
  short* D2W1B = (short*)(ws + 4456448);    //    262,144
  short* TCS   = (short*)(ws + 4718592);    //    393,216
  short* BASIS = (short*)(ws + 5111808);    //    393,216 (pad -> 6,291,456)
  short* XT    = (short*)(ws + 6291456);    // 25,165,824 [dead after fwdDFT]
  short* Y1    = XT;                        // big:100.7MB / small:50.3MB [FFN phase]
  short* QRI   = (short*)(ws + 31457280);   //  2,097,152
  short* OUTM  = (short*)(ws + 33554432);   //  2,097,152
  short* WTR   = (short*)(ws + 35651584);   // 33,554,432 [dead after modes]
  short* X1B   = WTR;                       // 25,165,824 [alias]
  short* WTI   = (short*)(ws + 69206016);   // 33,554,432 [dead after modes]
  short* X2B   = (short*)(ws + (big ? 106954752 : 60817408));   // 25,165,824
  short* H     = (short*)(ws + (big ? 132120576 : 85983232));   // 12,582,912

  prep_all<<<3840, 256, 0, stream>>>(conv1_w, conv2_w, d1_w1, d2_w1,
                                     C1WB, C2WB, D1W1B, D2W1B, TCS, BASIS);
  transpose_w<<<dim3(8, 512, 8), 256, 0, stream>>>(w_real, w_imag, WTR, WTI);
  transpose_x<<<dim3(8, 24, 16), 256, 0, stream>>>(x, XT);

  gemm64<false, false><<<dim3(128, 2), 256, 0, stream>>>(
      XT, L_, TCS, L_, nullptr, QRI, 1, (long)B_ * D_, L_);

  mode_gemm<<<dim3(64, 8), 256, 0, stream>>>(QRI, QRI + 64 * B_ * D_, WTR, WTI, OUTM);

  gemm128<false, false, true, false><<<dim3(12, 4, 16), 256, 0, stream>>>(
      BASIS, 128, 0, OUTM, 128, (long)D_ * 128, nullptr,
      x, D_, (long)L_ * D_, X1B, D_, (long)L_ * D_, 128);

  gemm64<true, true><<<dim3(384, 4), 256, 0, stream>>>(
      X1B, D_, D1W1B, D_, d1_b1, H, HID, 1, D_);
  combine_kernel<false, true><<<dim3(24, 16), 512, 0, stream>>>(
      X1B, H, d1_w2, d1_b2, nullptr, X2B);

  // --- FFN via gemmT v3 (FFN1: BM=256, grid=3 exact CU-waves; FFN2: BM=192, grid=256=1/CU) ---
  {
    const int nchunk = big ? 1 : 2;
    const long rows = big ? 24576 : 12288;
    for (int rc = 0; rc < nchunk; ++rc) {
      short* Ain = X2B + (long)rc * rows * D_;
      gemmT<256, true, false><<<dim3((int)(rows / 256) * (DFF_ / 256)), 512, 0, stream>>>(
          Ain, D_, C1WB, D_, nullptr, 0, Y1, DFF_, D_, DFF_ / 256);
      gemmT<192, false, true><<<dim3((int)(rows / 192) * (D_ / 256)), 512, 0, stream>>>(
          Y1, DFF_, C2WB, DFF_, Ain, D_, Ain, D_, DFF_, D_ / 256);
    }
  }

  gemm64<true, true><<<dim3(384, 4), 256, 0, stream>>>(
      X2B, D_, D2W1B, D_, d2_b1, H, HID, 1, D_);
  combine_kernel<true, false><<<dim3(24, 16), 512, 0, stream>>>(
      X2B, H, d2_w2, d2_b2, OUT, nullptr);
}